// Round 8
// baseline (1018.664 us; speedup 1.0000x reference)
//
#include <hip/hip_runtime.h>
#include <hip/hip_bf16.h>
#include <math.h>

#define PSPLIT 8
#define BSH 8                  // bucket = dst >> BSH  (256 dsts/bucket)
#define NBMAX 512              // max buckets (N <= 131072, matches 17-bit src pack)
#define CHUNK 8192             // edges per bscat block (32KB LDS staging)
#define AST 40                 // LDS row stride in shorts (80B: 16B-aligned, 2-way banks max)

typedef float v4f __attribute__((ext_vector_type(4)));
typedef float v2f __attribute__((ext_vector_type(2)));
typedef unsigned int v4u __attribute__((ext_vector_type(4)));
typedef unsigned int v2u __attribute__((ext_vector_type(2)));
typedef __attribute__((ext_vector_type(8))) short bf8;
typedef __attribute__((ext_vector_type(4))) float f4;
typedef unsigned short u16;
typedef unsigned int u32;

static inline size_t align_up(size_t x, size_t a){ return (x + a - 1) & ~(a - 1); }

__device__ inline void bf_split(float v, u16& hi, u16& lo){
  __hip_bfloat16 h = __float2bfloat16(v);
  float hf = __bfloat162float(h);
  __hip_bfloat16 l = __float2bfloat16(v - hf);
  hi = *(u16*)&h; lo = *(u16*)&l;
}

// fused fp16->f32 convert + accumulate: a += (float)lo16(p) / hi16(p).
__device__ inline void fmixlo(float& a, u32 p){
  asm("v_fma_mix_f32 %0, %1, 1.0, %0 op_sel:[0,0,0] op_sel_hi:[1,0,0]" : "+v"(a) : "v"(p));
}
__device__ inline void fmixhi(float& a, u32 p){
  asm("v_fma_mix_f32 %0, %1, 1.0, %0 op_sel:[1,0,0] op_sel_hi:[1,0,0]" : "+v"(a) : "v"(p));
}

__device__ inline float f16lo(u32 p){ u16 q = (u16)p; return (float)*(_Float16*)&q; }
__device__ inline float f16hi(u32 p){ u16 q = (u16)(p >> 16); return (float)*(_Float16*)&q; }

// fast tanh: 1 - 2/(exp2(2*log2e*x)+1).  v_exp+v_rcp, ~4e-7 abs err, inf/NaN-safe.
__device__ inline float tanh_fast(float x){
  float u = __builtin_amdgcn_exp2f(x * 2.8853900817779268f);
  float q = __builtin_amdgcn_rcpf(u + 1.0f);
  return fmaf(-2.0f, q, 1.0f);
}

// ---------------- graph prep: bucketed CSR build ----------------
// R17 multisplit (verified R5): LDS-staged, coalesced full-line copy-out.

__global__ __launch_bounds__(256) void k_bhist(const int* __restrict__ col, int* __restrict__ bcnt,
                                               int E, int NB,
                                               const int* __restrict__ batch, int* __restrict__ gstart,
                                               int n, int G){
  extern __shared__ int lh[];
  for (int i = threadIdx.x; i < NB; i += 256) lh[i] = 0;
  __syncthreads();
  for (int e = blockIdx.x * 256 + threadIdx.x; e < E; e += gridDim.x * 256)
    atomicAdd(&lh[col[e] >> BSH], 1);
  __syncthreads();
  for (int i = threadIdx.x; i < NB; i += 256){
    int v = lh[i];
    if (v) atomicAdd(&bcnt[i], v);
  }
  // fused gstart
  for (int i = blockIdx.x * 256 + threadIdx.x; i < n; i += gridDim.x * 256){
    int cb = batch[i];
    if (i == 0){ for (int g = 0; g <= cb; ++g) gstart[g] = 0; }
    else { int pb = batch[i - 1]; for (int g = pb + 1; g <= cb; ++g) gstart[g] = i; }
    if (i == n - 1){ for (int g = cb + 1; g <= G; ++g) gstart[g] = n; }
  }
}

__global__ void k_bscan(const int* __restrict__ bcnt, int* __restrict__ boff, int NB, int E,
                        int* __restrict__ rp, int N){
  __shared__ int sd[256];
  int t = threadIdx.x;
  int c[16]; int s = 0;
  const int PT = (NB + 255) / 256;   // <= 2 at BSH=8
  for (int j = 0; j < PT; ++j){ int i = t * PT + j; c[j] = (i < NB) ? bcnt[i] : 0; s += c[j]; }
  sd[t] = s; __syncthreads();
  for (int off = 1; off < 256; off <<= 1){
    int v = sd[t];
    if (t >= off) v += sd[t - off];
    __syncthreads(); sd[t] = v; __syncthreads();
  }
  int run = sd[t] - s;
  for (int j = 0; j < PT; ++j){ int i = t * PT + j; if (i < NB) boff[i] = run; run += c[j]; }
  if (t == 255){ boff[NB] = run; rp[N] = E; }
}

// LDS-staged multisplit scatter: per block, histogram 8192 edges over <=512 buckets,
// claim per-(block,bucket) global ranges (1 atomic per non-empty bucket), rank edges
// into LDS staging, copy out per-bucket runs coalesced -> full-line global writes.
__global__ __launch_bounds__(256) void k_bscat(const int* __restrict__ ei, const int* __restrict__ boff,
                                               int* __restrict__ bfill, unsigned* __restrict__ tmp,
                                               int E, int NB){
  __shared__ int lh[NBMAX], loff[NBMAX], gb[NBMAX], lfil[NBMAX];
  __shared__ int sd[256];
  __shared__ int sumA;
  __shared__ u32 stg[CHUNK];
  int t = threadIdx.x;
  const int* col = ei + E;
  int c0 = blockIdx.x * CHUNK;
  int c1 = c0 + CHUNK; if (c1 > E) c1 = E;

  for (int i = t; i < NBMAX; i += 256){ lh[i] = 0; lfil[i] = 0; }
  __syncthreads();
  // pass 1: local histogram
  for (int e = c0 + t; e < c1; e += 256)
    atomicAdd(&lh[col[e] >> BSH], 1);
  __syncthreads();
  // exclusive scan of lh[0..511] -> loff (two 256-cell tiers)
  sd[t] = lh[t]; __syncthreads();
  for (int off = 1; off < 256; off <<= 1){
    int v = sd[t];
    if (t >= off) v += sd[t - off];
    __syncthreads(); sd[t] = v; __syncthreads();
  }
  loff[t] = sd[t] - lh[t];
  if (t == 255) sumA = sd[255];
  __syncthreads();
  int lb = lh[256 + t];
  sd[t] = lb; __syncthreads();
  for (int off = 1; off < 256; off <<= 1){
    int v = sd[t];
    if (t >= off) v += sd[t - off];
    __syncthreads(); sd[t] = v; __syncthreads();
  }
  loff[256 + t] = sumA + sd[t] - lb;
  // claim global ranges
  for (int i = t; i < NB; i += 256){
    int c = lh[i];
    gb[i] = c ? (boff[i] + atomicAdd(&bfill[i * 16], c)) : 0;
  }
  __syncthreads();
  // pass 2: rank + stage
  for (int e = c0 + t; e < c1; e += 256){
    int d = col[e], s = ei[e];
    int b = d >> BSH;
    int p = atomicAdd(&lfil[b], 1);
    stg[loff[b] + p] = (unsigned)s | ((unsigned)(d & 255) << 17);
  }
  __syncthreads();
  // copy-out: wave w handles buckets w, w+4, ... (coalesced per-bucket runs)
  int wv = t >> 6, lane = t & 63;
  for (int b = wv; b < NB; b += 4){
    int len = lh[b];
    if (!len) continue;
    int base = gb[b], lo = loff[b];
    for (int j = lane; j < len; j += 64) tmp[base + j] = stg[lo + j];
  }
}

// per-bucket 256-bin counting sort: reads coalesced, writes 64B per-dst runs
// inside the block's own 16KB ssrc window.
__global__ __launch_bounds__(256) void k_bfin(const unsigned* __restrict__ tmp, const int* __restrict__ boff,
                                              int* __restrict__ ssrc, int* __restrict__ rp,
                                              float* __restrict__ dinv, int N){
  int b = blockIdx.x;
  int d0 = b << BSH;
  int lim = N - d0; if (lim > 256) lim = 256;
  __shared__ int dcnt[256], dexc[256], lfill[256];
  int t = threadIdx.x;
  dcnt[t] = 0; lfill[t] = 0;
  __syncthreads();
  int lo = boff[b], hi = boff[b + 1];
  for (int i = lo + t; i < hi; i += 256) atomicAdd(&dcnt[tmp[i] >> 17], 1);
  __syncthreads();
  int cme = dcnt[t];
  dexc[t] = cme; __syncthreads();
  for (int off = 1; off < 256; off <<= 1){
    int v = dexc[t];
    if (t >= off) v += dexc[t - off];
    __syncthreads(); dexc[t] = v; __syncthreads();
  }
  int excl = dexc[t] - cme;
  __syncthreads();
  dexc[t] = excl;
  if (t < lim){
    int d = d0 + t;
    rp[d] = lo + excl;
    double dd = (double)(cme + 1);               // +1 self-loop
    dinv[d] = (float)(1.0 / sqrt(dd));
  }
  __syncthreads();
  for (int i = lo + t; i < hi; i += 256){
    unsigned r = tmp[i];
    int l = r >> 17;
    int pos = dexc[l] + atomicAdd(&lfill[l], 1);
    ssrc[lo + pos] = (int)(r & 0x1FFFFu);
  }
}

// ---------------- W conversion: f32 [k][n] -> bf16 hi/lo TRANSPOSED [l][n][k] ----------------

__global__ __launch_bounds__(256) void k_cvtw(const float* __restrict__ w0, const float* __restrict__ w1,
                                              const float* __restrict__ w2, const float* __restrict__ w3,
                                              u16* __restrict__ wth, u16* __restrict__ wtl){
  int id = blockIdx.x * 256 + threadIdx.x;
  if (id >= 4 * 16384) return;
  int l = id >> 14, rem = id & 16383, k = rem >> 7, nn = rem & 127;
  const float* Wsrc = (l == 0) ? w0 : (l == 1) ? w1 : (l == 2) ? w2 : w3;
  float v = Wsrc[k * 128 + nn];
  u16 hi, lo; bf_split(v, hi, lo);
  wth[(l << 14) + nn * 128 + k] = hi;
  wtl[(l << 14) + nn * 128 + k] = lo;
}

// ---------------- GEMM (MFMA): C[N,128] = (A[N,128] @ W[128,128]) * dinv[row] ----------------
// R12 measured-best structure, ONE MFMA path (split-bf16, 3-term; lo*lo ~1e-6 dropped).
// packed=0 (layer 0): A f32 row-major. packed=1: A fp16-packed FEATURE-SLICED [8][n][16].
// R19: C (=hw) written feature-sliced [8][n][16 feats] fp16 -> slice nt goes to
// C + nt*n*16. Thread 16-feature chunks align exactly with slices on both read+write.

__global__ __launch_bounds__(256, 4) void k_gemm(const float* __restrict__ A,
                                                 const u16* __restrict__ wth, const u16* __restrict__ wtl,
                                                 const float* __restrict__ dinv,
                                                 u16* __restrict__ C, int n, int packed){
  __shared__ u16 Ah[128 * AST], Al[128 * AST], Wh[128 * AST], Wl[128 * AST];
  int t = threadIdx.x;
  int r0 = blockIdx.x * 128;
  int wv = t >> 6, lane = t & 63;
  int q = lane >> 4, ln = lane & 15;

  int srow = t >> 1;               // 0..127
  int shalf = (t & 1) * 16;        // k-offset within 32-chunk
  int grow = r0 + srow; if (grow > n - 1) grow = n - 1;
  const float* ga = A + (size_t)grow * 128 + shalf;   // f32 path (layer 0)
  const u16* gwh = wth + srow * 128 + shalf;
  const u16* gwl = wtl + srow * 128 + shalf;

  f4 acc[2][8];
  #pragma unroll
  for (int mt = 0; mt < 2; ++mt)
    #pragma unroll
    for (int nt = 0; nt < 8; ++nt) acc[mt][nt] = (f4)(0.f);

  for (int c = 0; c < 4; ++c){
    __syncthreads();
    // stage A chunk: 16 elems per thread -> hi/lo bf16 planes
    {
      u16* ah = &Ah[srow * AST + shalf];
      u16* al = &Al[srow * AST + shalf];
      if (packed){
        // sliced layout: features [32c+shalf, +16) = slice 2c + shalf/16, u32 offset 0..7
        const u32* gp32 = (const u32*)A + ((size_t)(2 * c + (shalf >> 4)) * n + grow) * 8;
        v4u vv0 = *(const v4u*)gp32;
        v4u vv1 = *(const v4u*)(gp32 + 4);
        u32 w_[8] = {vv0.x, vv0.y, vv0.z, vv0.w, vv1.x, vv1.y, vv1.z, vv1.w};
        #pragma unroll
        for (int i = 0; i < 4; ++i){
          u32 wa = w_[i * 2], wb = w_[i * 2 + 1];
          float x0 = f16lo(wa), x1 = f16hi(wa), x2 = f16lo(wb), x3 = f16hi(wb);
          u16 h0,h1,h2,h3,l0,l1,l2,l3;
          bf_split(x0, h0, l0); bf_split(x1, h1, l1);
          bf_split(x2, h2, l2); bf_split(x3, h3, l3);
          ushort4 hv = {h0,h1,h2,h3}, lv = {l0,l1,l2,l3};
          *(ushort4*)&ah[i * 4] = hv;
          *(ushort4*)&al[i * 4] = lv;
        }
      } else {
        const float4* gp = (const float4*)(ga + c * 32);
        #pragma unroll
        for (int i = 0; i < 4; ++i){
          float4 v = gp[i];
          u16 h0,h1,h2,h3,l0,l1,l2,l3;
          bf_split(v.x, h0, l0); bf_split(v.y, h1, l1);
          bf_split(v.z, h2, l2); bf_split(v.w, h3, l3);
          ushort4 hv = {h0,h1,h2,h3}, lv = {l0,l1,l2,l3};
          *(ushort4*)&ah[i * 4] = hv;
          *(ushort4*)&al[i * 4] = lv;
        }
      }
    }
    // stage W^T chunk
    {
      const u16* ph = gwh + c * 32;
      const u16* pl = gwl + c * 32;
      bf8 h0 = *(const bf8*)ph, h1 = *(const bf8*)(ph + 8);
      bf8 l0 = *(const bf8*)pl, l1 = *(const bf8*)(pl + 8);
      *(bf8*)&Wh[srow * AST + shalf] = h0; *(bf8*)&Wh[srow * AST + shalf + 8] = h1;
      *(bf8*)&Wl[srow * AST + shalf] = l0; *(bf8*)&Wl[srow * AST + shalf + 8] = l1;
    }
    __syncthreads();

    bf8 afh[2], afl[2];
    #pragma unroll
    for (int mt = 0; mt < 2; ++mt){
      int row = wv * 32 + mt * 16 + ln;
      afh[mt] = *(const bf8*)&Ah[row * AST + q * 8];
      afl[mt] = *(const bf8*)&Al[row * AST + q * 8];
    }
    #pragma unroll
    for (int nt = 0; nt < 8; ++nt){
      int wn = nt * 16 + ln;
      bf8 wfh = *(const bf8*)&Wh[wn * AST + q * 8];
      bf8 wfl = *(const bf8*)&Wl[wn * AST + q * 8];
      #pragma unroll
      for (int mt = 0; mt < 2; ++mt){
        acc[mt][nt] = __builtin_amdgcn_mfma_f32_16x16x32_bf16(afh[mt], wfh, acc[mt][nt], 0, 0, 0);
        acc[mt][nt] = __builtin_amdgcn_mfma_f32_16x16x32_bf16(afl[mt], wfh, acc[mt][nt], 0, 0, 0);
        acc[mt][nt] = __builtin_amdgcn_mfma_f32_16x16x32_bf16(afh[mt], wfl, acc[mt][nt], 0, 0, 0);
      }
    }
  }

  #pragma unroll
  for (int mt = 0; mt < 2; ++mt){
    int base_m = r0 + wv * 32 + mt * 16 + q * 4;
    float dv[4];
    #pragma unroll
    for (int reg = 0; reg < 4; ++reg){
      int row = base_m + reg;
      dv[reg] = (row < n) ? dinv[row] : 0.f;
    }
    #pragma unroll
    for (int nt = 0; nt < 8; ++nt){
      u16* Cs = C + (size_t)nt * n * 16;       // slice nt
      #pragma unroll
      for (int reg = 0; reg < 4; ++reg){
        int row = base_m + reg;
        if (row < n){
          _Float16 hv = (_Float16)(acc[mt][nt][reg] * dv[reg]);
          Cs[(size_t)row * 16 + ln] = *(u16*)&hv;
        }
      }
    }
  }
}

// ---------------- aggregate: h_out = tanh(dinv[d]*(sum hw'[src] + hw'[d]) + b) ----------------
// R19 structure: FEATURE-SLICED. hw/h are [8][n][16 feats] fp16; block handles slice = bid&7
// (XCD-local 3.2MB working set if bid%8 -> XCD round-robin holds; bounded loss if not).
// Wave = 1 node-slice: 8 edge slots x 8 lanes, lane owns 1 u32 = 2 features.
// Per 8 edges: 1 shfl + 1 load + 2 fmix per lane. 3-round shfl_down reduce over slots.

__global__ __launch_bounds__(256) void k_agg(const u16* __restrict__ hwp, const int* __restrict__ rp,
                                             const int* __restrict__ ssrc,
                                             const float* __restrict__ dinv, const float* __restrict__ bias,
                                             u32* __restrict__ hout, int n){
  int slice = blockIdx.x & 7;
  int node = (blockIdx.x >> 3) * 4 + (threadIdx.x >> 6);
  node = __builtin_amdgcn_readfirstlane(node);
  if (node >= n) return;
  int lane = threadIdx.x & 63;
  int el = lane >> 3;                  // edge slot 0..7
  int fl = lane & 7;                   // u32 within 32B slice-row
  size_t sstr = (size_t)n * 8;         // slice stride in u32
  const u32* base = (const u32*)hwp + (size_t)slice * sstr + fl;

  int e0 = rp[node], e1 = rp[node + 1];
  float a0 = 0.f, a1 = 0.f;
  for (int eb = e0; eb < e1; eb += 64){
    int m = e1 - eb; if (m > 64) m = 64;
    int sl = (lane < m) ? ssrc[eb + lane] : 0;
    int mp = m & ~7;
    int j = 0;
    for (; j + 32 <= mp; j += 32){
      int s0 = __shfl(sl, j + el),      s1 = __shfl(sl, j + 8 + el);
      int s2 = __shfl(sl, j + 16 + el), s3 = __shfl(sl, j + 24 + el);
      u32 p0 = base[(size_t)s0 * 8], p1 = base[(size_t)s1 * 8];
      u32 p2 = base[(size_t)s2 * 8], p3 = base[(size_t)s3 * 8];
      fmixlo(a0, p0); fmixhi(a1, p0); fmixlo(a0, p1); fmixhi(a1, p1);
      fmixlo(a0, p2); fmixhi(a1, p2); fmixlo(a0, p3); fmixhi(a1, p3);
    }
    if (j + 16 <= mp){
      int s0 = __shfl(sl, j + el), s1 = __shfl(sl, j + 8 + el);
      u32 p0 = base[(size_t)s0 * 8], p1 = base[(size_t)s1 * 8];
      fmixlo(a0, p0); fmixhi(a1, p0); fmixlo(a0, p1); fmixhi(a1, p1);
      j += 16;
    }
    if (j + 8 <= mp){
      int s0 = __shfl(sl, j + el);
      u32 p0 = base[(size_t)s0 * 8];
      fmixlo(a0, p0); fmixhi(a1, p0);
      j += 8;
    }
    if (j < m){
      int s0 = __shfl(sl, j + el);
      if (j + el < m){
        u32 p0 = base[(size_t)s0 * 8];
        fmixlo(a0, p0); fmixhi(a1, p0);
      }
    }
  }
  // reduce across the 8 edge slots -> lanes 0..7
  a0 += __shfl_down(a0, 32); a1 += __shfl_down(a1, 32);
  a0 += __shfl_down(a0, 16); a1 += __shfl_down(a1, 16);
  a0 += __shfl_down(a0, 8);  a1 += __shfl_down(a1, 8);
  if (lane < 8){
    u32 p = base[(size_t)node * 8];    // self term (already * dinv[node])
    fmixlo(a0, p); fmixhi(a1, p);
    float di = dinv[node];
    v2f bv = *(const v2f*)(bias + slice * 16 + fl * 2);
    float r0 = tanh_fast(fmaf(a0, di, bv.x));
    float r1 = tanh_fast(fmaf(a1, di, bv.y));
    _Float16 f0 = (_Float16)r0, f1 = (_Float16)r1;
    u32 pv = ((u32)(*(u16*)&f1) << 16) | (u32)(*(u16*)&f0);
    __builtin_nontemporal_store(pv, hout + (size_t)slice * sstr + (size_t)node * 8 + fl);
  }
}

// ---------------- pool: stage 1 partial max/sum over fp16-packed SLICED h ----------------

__global__ __launch_bounds__(256) void k_pool1(const u32* __restrict__ h, const int* __restrict__ gstart,
                                               float* __restrict__ pmx, float* __restrict__ psm, int n){
  int g = blockIdx.x >> 3, s = blockIdx.x & (PSPLIT - 1);
  int t = threadIdx.x;
  int fq = t & 31;             // feature quad (4 features = 2 u32); sliced addr, identity pmx map
  int rw = t >> 5;             // row slot 0..7
  int i0 = gstart[g], i1 = gstart[g + 1];
  int len = i1 - i0;
  int chunk = (len + PSPLIT - 1) / PSPLIT;
  int a = i0 + s * chunk;
  int b = a + chunk; if (b > i1) b = i1;

  const u32* sb = h + (size_t)(fq >> 2) * n * 8 + (fq & 3) * 2;   // slice base + quad offset
  v4f mx = (v4f)(-INFINITY), sm = (v4f)(0.f);
  for (int i = a + rw; i < b; i += 8){
    v2u p = *(const v2u*)(sb + (size_t)i * 8);
    float x0 = f16lo(p.x), x1 = f16hi(p.x), x2 = f16lo(p.y), x3 = f16hi(p.y);
    mx.x = fmaxf(mx.x, x0); mx.y = fmaxf(mx.y, x1);
    mx.z = fmaxf(mx.z, x2); mx.w = fmaxf(mx.w, x3);
    sm.x += x0; sm.y += x1; sm.z += x2; sm.w += x3;
  }
  __shared__ v4f smx[8][32], ssm[8][32];
  smx[rw][fq] = mx; ssm[rw][fq] = sm;
  __syncthreads();
  if (rw == 0){
    #pragma unroll
    for (int r2 = 1; r2 < 8; ++r2){
      v4f m2 = smx[r2][fq], s2 = ssm[r2][fq];
      mx.x = fmaxf(mx.x, m2.x); mx.y = fmaxf(mx.y, m2.y);
      mx.z = fmaxf(mx.z, m2.z); mx.w = fmaxf(mx.w, m2.w);
      sm += s2;
    }
    ((v4f*)pmx)[(size_t)blockIdx.x * 32 + fq] = mx;
    ((v4f*)psm)[(size_t)blockIdx.x * 32 + fq] = sm;
  }
}

__global__ __launch_bounds__(128) void k_head(const float* __restrict__ pmx, const float* __restrict__ psm,
                                              const int* __restrict__ gstart,
                                              const float* __restrict__ Wl, const float* __restrict__ bl,
                                              float* __restrict__ out){
  int g = blockIdx.x, f = threadIdx.x;
  float mx = -INFINITY, sm = 0.f;
  #pragma unroll
  for (int s = 0; s < PSPLIT; ++s){
    mx = fmaxf(mx, pmx[((size_t)g * PSPLIT + s) * 128 + f]);
    sm += psm[((size_t)g * PSPLIT + s) * 128 + f];
  }
  int cnt = gstart[g + 1] - gstart[g];
  if (cnt <= 0) mx = 0.f;
  float mn = sm / (float)(cnt > 0 ? cnt : 1);
  float contrib = mx * Wl[f] + mn * Wl[128 + f];
  for (int o = 32; o > 0; o >>= 1) contrib += __shfl_down(contrib, o);
  __shared__ float sred[2];
  if ((f & 63) == 0) sred[f >> 6] = contrib;
  __syncthreads();
  if (f == 0) out[g] = sred[0] + sred[1] + bl[0];
}

// ---------------- launch ----------------

extern "C" void kernel_launch(void* const* d_in, const int* in_sizes, int n_in,
                              void* d_out, int out_size, void* d_ws, size_t ws_size,
                              hipStream_t stream){
  const float* x     = (const float*)d_in[0];
  const int*   ei    = (const int*)d_in[1];
  const int*   batch = (const int*)d_in[2];
  const float* W[4]  = {(const float*)d_in[3], (const float*)d_in[5], (const float*)d_in[7], (const float*)d_in[9]};
  const float* B[4]  = {(const float*)d_in[4], (const float*)d_in[6], (const float*)d_in[8], (const float*)d_in[10]};
  const float* Wl    = (const float*)d_in[11];
  const float* bl    = (const float*)d_in[12];
  float* out = (float*)d_out;

  int N = in_sizes[0] / 128;
  int E = in_sizes[1] / 2;
  int G = out_size;
  int NB = (N + 255) >> BSH;

  char* ws = (char*)d_ws;
  size_t off = 0;
  auto alloc = [&](size_t bytes) -> void* {
    void* p = ws + off; off = align_up(off + bytes, 256); return p;
  };
  float* dinv  = (float*)alloc((size_t)N * 4);
  int*   rp    = (int*)  alloc((size_t)(N + 1) * 4);
  int*   bcnt  = (int*)  alloc((size_t)(NB + 1) * 4);
  int*   boff  = (int*)  alloc((size_t)(NB + 1) * 4);
  int*   bfill = (int*)  alloc((size_t)NB * 16 * 4);   // 64B-padded claim counters
  int*   gst   = (int*)  alloc((size_t)(G + 1) * 4);
  int*   ssrc  = (int*)  alloc((size_t)E * 4);
  u16*   wth   = (u16*)  alloc((size_t)4 * 16384 * 2);
  u16*   wtl   = (u16*)  alloc((size_t)4 * 16384 * 2);
  float* pmx   = (float*)alloc((size_t)G * PSPLIT * 128 * 4);
  float* psm   = (float*)alloc((size_t)G * PSPLIT * 128 * 4);
  u16*   hw    = (u16*)  alloc((size_t)N * 128 * 2);   // fp16 message buffer, sliced [8][N][16]
  u32*   h     = (u32*)  alloc((size_t)N * 64 * 4);    // fp16-packed activations, sliced
  unsigned* tmp = (unsigned*)hw;   // alias: tmp (E*4=6.4MB) dead before first gemm writes hw (25.6MB)

  hipMemsetAsync(bcnt, 0, (size_t)(NB + 1) * 4, stream);
  hipMemsetAsync(bfill, 0, (size_t)NB * 16 * 4, stream);

  k_cvtw <<<256, 256, 0, stream>>>(W[0], W[1], W[2], W[3], wth, wtl);
  k_bhist<<<128, 256, NB * 4, stream>>>(ei + E, bcnt, E, NB, batch, gst, N, G);
  k_bscan<<<1, 256, 0, stream>>>(bcnt, boff, NB, E, rp, N);
  k_bscat<<<(E + CHUNK - 1) / CHUNK, 256, 0, stream>>>(ei, boff, bfill, tmp, E, NB);
  k_bfin <<<NB, 256, 0, stream>>>(tmp, boff, ssrc, rp, dinv, N);

  int gemmG = (N + 127) / 128;
  int aggG  = 8 * ((N + 3) / 4);           // 8 slices x node-quads, slice = bid & 7
  const float* hin = x;
  for (int l = 0; l < 4; ++l){
    k_gemm<<<gemmG, 256, 0, stream>>>(hin, wth + (l << 14), wtl + (l << 14), dinv, hw, N, l > 0);
    k_agg <<<aggG, 256, 0, stream>>>(hw, rp, ssrc, dinv, B[l], h, N);
    hin = (const float*)h;
  }
  k_pool1<<<G * PSPLIT, 256, 0, stream>>>(h, gst, pmx, psm, N);
  k_head <<<G, 128, 0, stream>>>(pmx, psm, gst, Wl, bl, out);
}

// Round 11
// 699.734 us; speedup vs baseline: 1.4558x; 1.4558x over previous
//
// R20-resubmit-v3 (R10→R11): semantically identical to R9/R10 submission; comments
// touched only to perturb the source hash (rule out corrupted cached artifact).
#include <hip/hip_runtime.h>
#include <hip/hip_bf16.h>
#include <math.h>

#define PSPLIT 8
#define BSH 8                  // bucket = dst >> BSH  (256 dsts/bucket)
#define NBMAX 512              // max buckets (N <= 131072, matches 17-bit src pack)
#define CHUNK 8192             // edges per bscat block (32KB LDS staging)
#define AST 40                 // LDS row stride in shorts (80B: 16B-aligned, 2-way banks max)

typedef float v4f __attribute__((ext_vector_type(4)));
typedef float v2f __attribute__((ext_vector_type(2)));
typedef unsigned int v4u __attribute__((ext_vector_type(4)));
typedef unsigned int v2u __attribute__((ext_vector_type(2)));
typedef __attribute__((ext_vector_type(8))) short bf8;
typedef __attribute__((ext_vector_type(4))) float f4;
typedef unsigned short u16;
typedef unsigned int u32;

static inline size_t align_up(size_t x, size_t a){ return (x + a - 1) & ~(a - 1); }

__device__ inline void bf_split(float v, u16& hi, u16& lo){
  __hip_bfloat16 h = __float2bfloat16(v);
  float hf = __bfloat162float(h);
  __hip_bfloat16 l = __float2bfloat16(v - hf);
  hi = *(u16*)&h; lo = *(u16*)&l;
}

// fused fp16->f32 convert + accumulate: a += (float)lo16(p) / hi16(p).
__device__ inline void fmixlo(float& a, u32 p){
  asm("v_fma_mix_f32 %0, %1, 1.0, %0 op_sel:[0,0,0] op_sel_hi:[1,0,0]" : "+v"(a) : "v"(p));
}
__device__ inline void fmixhi(float& a, u32 p){
  asm("v_fma_mix_f32 %0, %1, 1.0, %0 op_sel:[1,0,0] op_sel_hi:[1,0,0]" : "+v"(a) : "v"(p));
}

__device__ inline float f16lo(u32 p){ u16 q = (u16)p; return (float)*(_Float16*)&q; }
__device__ inline float f16hi(u32 p){ u16 q = (u16)(p >> 16); return (float)*(_Float16*)&q; }

// fast tanh: 1 - 2/(exp2(2*log2e*x)+1).  v_exp+v_rcp, ~4e-7 abs err, inf/NaN-safe.
__device__ inline float tanh_fast(float x){
  float u = __builtin_amdgcn_exp2f(x * 2.8853900817779268f);
  float q = __builtin_amdgcn_rcpf(u + 1.0f);
  return fmaf(-2.0f, q, 1.0f);
}

// ---------------- graph prep: bucketed CSR build ----------------

__global__ __launch_bounds__(256) void k_bhist(const int* __restrict__ col, int* __restrict__ bcnt,
                                               int E, int NB,
                                               const int* __restrict__ batch, int* __restrict__ gstart,
                                               int n, int G){
  extern __shared__ int lh[];
  for (int i = threadIdx.x; i < NB; i += 256) lh[i] = 0;
  __syncthreads();
  for (int e = blockIdx.x * 256 + threadIdx.x; e < E; e += gridDim.x * 256)
    atomicAdd(&lh[col[e] >> BSH], 1);
  __syncthreads();
  for (int i = threadIdx.x; i < NB; i += 256){
    int v = lh[i];
    if (v) atomicAdd(&bcnt[i], v);
  }
  // fused gstart
  for (int i = blockIdx.x * 256 + threadIdx.x; i < n; i += gridDim.x * 256){
    int cb = batch[i];
    if (i == 0){ for (int g = 0; g <= cb; ++g) gstart[g] = 0; }
    else { int pb = batch[i - 1]; for (int g = pb + 1; g <= cb; ++g) gstart[g] = i; }
    if (i == n - 1){ for (int g = cb + 1; g <= G; ++g) gstart[g] = n; }
  }
}

__global__ void k_bscan(const int* __restrict__ bcnt, int* __restrict__ boff, int NB, int E,
                        int* __restrict__ rp, int N){
  __shared__ int sd[256];
  int t = threadIdx.x;
  int c[16]; int s = 0;
  const int PT = (NB + 255) / 256;   // <= 2 at BSH=8
  for (int j = 0; j < PT; ++j){ int i = t * PT + j; c[j] = (i < NB) ? bcnt[i] : 0; s += c[j]; }
  sd[t] = s; __syncthreads();
  for (int off = 1; off < 256; off <<= 1){
    int v = sd[t];
    if (t >= off) v += sd[t - off];
    __syncthreads(); sd[t] = v; __syncthreads();
  }
  int run = sd[t] - s;
  for (int j = 0; j < PT; ++j){ int i = t * PT + j; if (i < NB) boff[i] = run; run += c[j]; }
  if (t == 255){ boff[NB] = run; rp[N] = E; }
}

// LDS-staged multisplit scatter (verified R5): coalesced full-line copy-out.
__global__ __launch_bounds__(256) void k_bscat(const int* __restrict__ ei, const int* __restrict__ boff,
                                               int* __restrict__ bfill, unsigned* __restrict__ tmp,
                                               int E, int NB){
  __shared__ int lh[NBMAX], loff[NBMAX], gb[NBMAX], lfil[NBMAX];
  __shared__ int sd[256];
  __shared__ int sumA;
  __shared__ u32 stg[CHUNK];
  int t = threadIdx.x;
  const int* col = ei + E;
  int c0 = blockIdx.x * CHUNK;
  int c1 = c0 + CHUNK; if (c1 > E) c1 = E;

  for (int i = t; i < NBMAX; i += 256){ lh[i] = 0; lfil[i] = 0; }
  __syncthreads();
  // pass 1: local histogram
  for (int e = c0 + t; e < c1; e += 256)
    atomicAdd(&lh[col[e] >> BSH], 1);
  __syncthreads();
  // exclusive scan of lh[0..511] -> loff (two 256-cell tiers)
  sd[t] = lh[t]; __syncthreads();
  for (int off = 1; off < 256; off <<= 1){
    int v = sd[t];
    if (t >= off) v += sd[t - off];
    __syncthreads(); sd[t] = v; __syncthreads();
  }
  loff[t] = sd[t] - lh[t];
  if (t == 255) sumA = sd[255];
  __syncthreads();
  int lb = lh[256 + t];
  sd[t] = lb; __syncthreads();
  for (int off = 1; off < 256; off <<= 1){
    int v = sd[t];
    if (t >= off) v += sd[t - off];
    __syncthreads(); sd[t] = v; __syncthreads();
  }
  loff[256 + t] = sumA + sd[t] - lb;
  // claim global ranges
  for (int i = t; i < NB; i += 256){
    int c = lh[i];
    gb[i] = c ? (boff[i] + atomicAdd(&bfill[i * 16], c)) : 0;
  }
  __syncthreads();
  // pass 2: rank + stage
  for (int e = c0 + t; e < c1; e += 256){
    int d = col[e], s = ei[e];
    int b = d >> BSH;
    int p = atomicAdd(&lfil[b], 1);
    stg[loff[b] + p] = (unsigned)s | ((unsigned)(d & 255) << 17);
  }
  __syncthreads();
  // copy-out: wave w handles buckets w, w+4, ... (coalesced per-bucket runs)
  int wv = t >> 6, lane = t & 63;
  for (int b = wv; b < NB; b += 4){
    int len = lh[b];
    if (!len) continue;
    int base = gb[b], lo = loff[b];
    for (int j = lane; j < len; j += 64) tmp[base + j] = stg[lo + j];
  }
}

// per-bucket 256-bin counting sort (verified R5).
__global__ __launch_bounds__(256) void k_bfin(const unsigned* __restrict__ tmp, const int* __restrict__ boff,
                                              int* __restrict__ ssrc, int* __restrict__ rp,
                                              float* __restrict__ dinv, int N){
  int b = blockIdx.x;
  int d0 = b << BSH;
  int lim = N - d0; if (lim > 256) lim = 256;
  __shared__ int dcnt[256], dexc[256], lfill[256];
  int t = threadIdx.x;
  dcnt[t] = 0; lfill[t] = 0;
  __syncthreads();
  int lo = boff[b], hi = boff[b + 1];
  for (int i = lo + t; i < hi; i += 256) atomicAdd(&dcnt[tmp[i] >> 17], 1);
  __syncthreads();
  int cme = dcnt[t];
  dexc[t] = cme; __syncthreads();
  for (int off = 1; off < 256; off <<= 1){
    int v = dexc[t];
    if (t >= off) v += dexc[t - off];
    __syncthreads(); dexc[t] = v; __syncthreads();
  }
  int excl = dexc[t] - cme;
  __syncthreads();
  dexc[t] = excl;
  if (t < lim){
    int d = d0 + t;
    rp[d] = lo + excl;
    double dd = (double)(cme + 1);               // +1 self-loop
    dinv[d] = (float)(1.0 / sqrt(dd));
  }
  __syncthreads();
  for (int i = lo + t; i < hi; i += 256){
    unsigned r = tmp[i];
    int l = r >> 17;
    int pos = dexc[l] + atomicAdd(&lfill[l], 1);
    ssrc[lo + pos] = (int)(r & 0x1FFFFu);
  }
}

// ---------------- W conversion: f32 [k][n] -> bf16 hi/lo TRANSPOSED [l][n][k] ----------------

__global__ __launch_bounds__(256) void k_cvtw(const float* __restrict__ w0, const float* __restrict__ w1,
                                              const float* __restrict__ w2, const float* __restrict__ w3,
                                              u16* __restrict__ wth, u16* __restrict__ wtl){
  int id = blockIdx.x * 256 + threadIdx.x;
  if (id >= 4 * 16384) return;
  int l = id >> 14, rem = id & 16383, k = rem >> 7, nn = rem & 127;
  const float* Wsrc = (l == 0) ? w0 : (l == 1) ? w1 : (l == 2) ? w2 : w3;
  float v = Wsrc[k * 128 + nn];
  u16 hi, lo; bf_split(v, hi, lo);
  wth[(l << 14) + nn * 128 + k] = hi;
  wtl[(l << 14) + nn * 128 + k] = lo;
}

// ---------------- GEMM (MFMA): C[N,128] = (A[N,128] @ W[128,128]) * dinv[row] ----------------
// Verified structure (R12/R7). Split-bf16 3-term MFMA, single code path.
// packed=0: A f32 row-major. packed=1: A fp16-packed feature-sliced [8][n][16].
// C written feature-sliced [8][n][16] fp16 (verified R8, absmax 7.6e-6).

__global__ __launch_bounds__(256, 4) void k_gemm(const float* __restrict__ A,
                                                 const u16* __restrict__ wth, const u16* __restrict__ wtl,
                                                 const float* __restrict__ dinv,
                                                 u16* __restrict__ C, int n, int packed){
  __shared__ u16 Ah[128 * AST], Al[128 * AST], Wh[128 * AST], Wl[128 * AST];
  int t = threadIdx.x;
  int r0 = blockIdx.x * 128;
  int wv = t >> 6, lane = t & 63;
  int q = lane >> 4, ln = lane & 15;

  int srow = t >> 1;               // 0..127
  int shalf = (t & 1) * 16;        // k-offset within 32-chunk
  int grow = r0 + srow; if (grow > n - 1) grow = n - 1;
  const float* ga = A + (size_t)grow * 128 + shalf;   // f32 path (layer 0)
  const u16* gwh = wth + srow * 128 + shalf;
  const u16* gwl = wtl + srow * 128 + shalf;

  f4 acc[2][8];
  #pragma unroll
  for (int mt = 0; mt < 2; ++mt)
    #pragma unroll
    for (int nt = 0; nt < 8; ++nt) acc[mt][nt] = (f4)(0.f);

  for (int c = 0; c < 4; ++c){
    __syncthreads();
    // stage A chunk: 16 elems per thread -> hi/lo bf16 planes
    {
      u16* ah = &Ah[srow * AST + shalf];
      u16* al = &Al[srow * AST + shalf];
      if (packed){
        // sliced layout: features [32c+shalf, +16) = slice 2c + shalf/16, u32 offset 0..7
        const u32* gp32 = (const u32*)A + ((size_t)(2 * c + (shalf >> 4)) * n + grow) * 8;
        v4u vv0 = *(const v4u*)gp32;
        v4u vv1 = *(const v4u*)(gp32 + 4);
        u32 w_[8] = {vv0.x, vv0.y, vv0.z, vv0.w, vv1.x, vv1.y, vv1.z, vv1.w};
        #pragma unroll
        for (int i = 0; i < 4; ++i){
          u32 wa = w_[i * 2], wb = w_[i * 2 + 1];
          float x0 = f16lo(wa), x1 = f16hi(wa), x2 = f16lo(wb), x3 = f16hi(wb);
          u16 h0,h1,h2,h3,l0,l1,l2,l3;
          bf_split(x0, h0, l0); bf_split(x1, h1, l1);
          bf_split(x2, h2, l2); bf_split(x3, h3, l3);
          ushort4 hv = {h0,h1,h2,h3}, lv = {l0,l1,l2,l3};
          *(ushort4*)&ah[i * 4] = hv;
          *(ushort4*)&al[i * 4] = lv;
        }
      } else {
        const float4* gp = (const float4*)(ga + c * 32);
        #pragma unroll
        for (int i = 0; i < 4; ++i){
          float4 v = gp[i];
          u16 h0,h1,h2,h3,l0,l1,l2,l3;
          bf_split(v.x, h0, l0); bf_split(v.y, h1, l1);
          bf_split(v.z, h2, l2); bf_split(v.w, h3, l3);
          ushort4 hv = {h0,h1,h2,h3}, lv = {l0,l1,l2,l3};
          *(ushort4*)&ah[i * 4] = hv;
          *(ushort4*)&al[i * 4] = lv;
        }
      }
    }
    // stage W^T chunk
    {
      const u16* ph = gwh + c * 32;
      const u16* pl = gwl + c * 32;
      bf8 h0 = *(const bf8*)ph, h1 = *(const bf8*)(ph + 8);
      bf8 l0 = *(const bf8*)pl, l1 = *(const bf8*)(pl + 8);
      *(bf8*)&Wh[srow * AST + shalf] = h0; *(bf8*)&Wh[srow * AST + shalf + 8] = h1;
      *(bf8*)&Wl[srow * AST + shalf] = l0; *(bf8*)&Wl[srow * AST + shalf + 8] = l1;
    }
    __syncthreads();

    bf8 afh[2], afl[2];
    #pragma unroll
    for (int mt = 0; mt < 2; ++mt){
      int row = wv * 32 + mt * 16 + ln;
      afh[mt] = *(const bf8*)&Ah[row * AST + q * 8];
      afl[mt] = *(const bf8*)&Al[row * AST + q * 8];
    }
    #pragma unroll
    for (int nt = 0; nt < 8; ++nt){
      int wn = nt * 16 + ln;
      bf8 wfh = *(const bf8*)&Wh[wn * AST + q * 8];
      bf8 wfl = *(const bf8*)&Wl[wn * AST + q * 8];
      #pragma unroll
      for (int mt = 0; mt < 2; ++mt){
        acc[mt][nt] = __builtin_amdgcn_mfma_f32_16x16x32_bf16(afh[mt], wfh, acc[mt][nt], 0, 0, 0);
        acc[mt][nt] = __builtin_amdgcn_mfma_f32_16x16x32_bf16(afl[mt], wfh, acc[mt][nt], 0, 0, 0);
        acc[mt][nt] = __builtin_amdgcn_mfma_f32_16x16x32_bf16(afh[mt], wfl, acc[mt][nt], 0, 0, 0);
      }
    }
  }

  #pragma unroll
  for (int mt = 0; mt < 2; ++mt){
    int base_m = r0 + wv * 32 + mt * 16 + q * 4;
    float dv[4];
    #pragma unroll
    for (int reg = 0; reg < 4; ++reg){
      int row = base_m + reg;
      dv[reg] = (row < n) ? dinv[row] : 0.f;
    }
    #pragma unroll
    for (int nt = 0; nt < 8; ++nt){
      u16* Cs = C + (size_t)nt * n * 16;       // slice nt
      #pragma unroll
      for (int reg = 0; reg < 4; ++reg){
        int row = base_m + reg;
        if (row < n){
          _Float16 hv = (_Float16)(acc[mt][nt][reg] * dv[reg]);
          Cs[(size_t)row * 16 + ln] = *(u16*)&hv;
        }
      }
    }
  }
}

// ---------------- aggregate: h_out = tanh(dinv[d]*(sum hw'[src] + hw'[d]) + b) ----------------
// R20: feature-sliced (L2-resident gathers, FETCH 44MB verified R8), fixed cost amortized
// 8x: wave = 8 nodes x 1 slice. 8-lane group walks its node's edges serially (exec-masked):
// 1 broadcast ssrc load + 32B gather + 2 fmix per edge. No shuffles, no reduce; epilogue
// once per 8 nodes; 256B coalesced stores. Bounds audit (R11): max u32 index 64N-1 < 64N.

__global__ __launch_bounds__(256) void k_agg(const u16* __restrict__ hwp, const int* __restrict__ rp,
                                             const int* __restrict__ ssrc,
                                             const float* __restrict__ dinv, const float* __restrict__ bias,
                                             u32* __restrict__ hout, int n){
  int slice = blockIdx.x & 7;
  int lane = threadIdx.x & 63;
  int el = lane >> 3;                  // node within oct (0..7)
  int fl = lane & 7;                   // u32 within 32B slice-row
  int node = (blockIdx.x >> 3) * 32 + (threadIdx.x >> 6) * 8 + el;
  size_t sstr = (size_t)n * 8;         // slice stride in u32
  const u32* base = (const u32*)hwp + (size_t)slice * sstr + fl;

  bool valid = node < n;
  int ee = valid ? rp[node] : 0;
  int e1 = valid ? rp[node + 1] : 0;
  float a0 = 0.f, a1 = 0.f;
  for (; ee + 2 <= e1; ee += 2){
    int s0 = ssrc[ee], s1 = ssrc[ee + 1];
    u32 p0 = base[(size_t)s0 * 8];
    u32 p1 = base[(size_t)s1 * 8];
    fmixlo(a0, p0); fmixhi(a1, p0);
    fmixlo(a0, p1); fmixhi(a1, p1);
  }
  if (ee < e1){
    int s0 = ssrc[ee];
    u32 p0 = base[(size_t)s0 * 8];
    fmixlo(a0, p0); fmixhi(a1, p0);
  }
  if (valid){
    u32 p = base[(size_t)node * 8];    // self term (already * dinv[node])
    fmixlo(a0, p); fmixhi(a1, p);
    float di = dinv[node];
    v2f bv = *(const v2f*)(bias + slice * 16 + fl * 2);
    float r0 = tanh_fast(fmaf(a0, di, bv.x));
    float r1 = tanh_fast(fmaf(a1, di, bv.y));
    _Float16 f0 = (_Float16)r0, f1 = (_Float16)r1;
    u32 pv = ((u32)(*(u16*)&f1) << 16) | (u32)(*(u16*)&f0);
    __builtin_nontemporal_store(pv, hout + (size_t)slice * sstr + (size_t)node * 8 + fl);
  }
}

// ---------------- pool: stage 1 partial max/sum over fp16-packed SLICED h ----------------

__global__ __launch_bounds__(256) void k_pool1(const u32* __restrict__ h, const int* __restrict__ gstart,
                                               float* __restrict__ pmx, float* __restrict__ psm, int n){
  int g = blockIdx.x >> 3, s = blockIdx.x & (PSPLIT - 1);
  int t = threadIdx.x;
  int fq = t & 31;             // feature quad (4 features = 2 u32); sliced addr, identity pmx map
  int rw = t >> 5;             // row slot 0..7
  int i0 = gstart[g], i1 = gstart[g + 1];
  int len = i1 - i0;
  int chunk = (len + PSPLIT - 1) / PSPLIT;
  int a = i0 + s * chunk;
  int b = a + chunk; if (b > i1) b = i1;

  const u32* sb = h + (size_t)(fq >> 2) * n * 8 + (fq & 3) * 2;   // slice base + quad offset
  v4f mx = (v4f)(-INFINITY), sm = (v4f)(0.f);
  for (int i = a + rw; i < b; i += 8){
    v2u p = *(const v2u*)(sb + (size_t)i * 8);
    float x0 = f16lo(p.x), x1 = f16hi(p.x), x2 = f16lo(p.y), x3 = f16hi(p.y);
    mx.x = fmaxf(mx.x, x0); mx.y = fmaxf(mx.y, x1);
    mx.z = fmaxf(mx.z, x2); mx.w = fmaxf(mx.w, x3);
    sm.x += x0; sm.y += x1; sm.z += x2; sm.w += x3;
  }
  __shared__ v4f smx[8][32], ssm[8][32];
  smx[rw][fq] = mx; ssm[rw][fq] = sm;
  __syncthreads();
  if (rw == 0){
    #pragma unroll
    for (int r2 = 1; r2 < 8; ++r2){
      v4f m2 = smx[r2][fq], s2 = ssm[r2][fq];
      mx.x = fmaxf(mx.x, m2.x); mx.y = fmaxf(mx.y, m2.y);
      mx.z = fmaxf(mx.z, m2.z); mx.w = fmaxf(mx.w, m2.w);
      sm += s2;
    }
    ((v4f*)pmx)[(size_t)blockIdx.x * 32 + fq] = mx;
    ((v4f*)psm)[(size_t)blockIdx.x * 32 + fq] = sm;
  }
}

__global__ __launch_bounds__(128) void k_head(const float* __restrict__ pmx, const float* __restrict__ psm,
                                              const int* __restrict__ gstart,
                                              const float* __restrict__ Wl, const float* __restrict__ bl,
                                              float* __restrict__ out){
  int g = blockIdx.x, f = threadIdx.x;
  float mx = -INFINITY, sm = 0.f;
  #pragma unroll
  for (int s = 0; s < PSPLIT; ++s){
    mx = fmaxf(mx, pmx[((size_t)g * PSPLIT + s) * 128 + f]);
    sm += psm[((size_t)g * PSPLIT + s) * 128 + f];
  }
  int cnt = gstart[g + 1] - gstart[g];
  if (cnt <= 0) mx = 0.f;
  float mn = sm / (float)(cnt > 0 ? cnt : 1);
  float contrib = mx * Wl[f] + mn * Wl[128 + f];
  for (int o = 32; o > 0; o >>= 1) contrib += __shfl_down(contrib, o);
  __shared__ float sred[2];
  if ((f & 63) == 0) sred[f >> 6] = contrib;
  __syncthreads();
  if (f == 0) out[g] = sred[0] + sred[1] + bl[0];
}

// ---------------- launch ----------------

extern "C" void kernel_launch(void* const* d_in, const int* in_sizes, int n_in,
                              void* d_out, int out_size, void* d_ws, size_t ws_size,
                              hipStream_t stream){
  const float* x     = (const float*)d_in[0];
  const int*   ei    = (const int*)d_in[1];
  const int*   batch = (const int*)d_in[2];
  const float* W[4]  = {(const float*)d_in[3], (const float*)d_in[5], (const float*)d_in[7], (const float*)d_in[9]};
  const float* B[4]  = {(const float*)d_in[4], (const float*)d_in[6], (const float*)d_in[8], (const float*)d_in[10]};
  const float* Wl    = (const float*)d_in[11];
  const float* bl    = (const float*)d_in[12];
  float* out = (float*)d_out;

  int N = in_sizes[0] / 128;
  int E = in_sizes[1] / 2;
  int G = out_size;
  int NB = (N + 255) >> BSH;

  char* ws = (char*)d_ws;
  size_t off = 0;
  auto alloc = [&](size_t bytes) -> void* {
    void* p = ws + off; off = align_up(off + bytes, 256); return p;
  };
  float* dinv  = (float*)alloc((size_t)N * 4);
  int*   rp    = (int*)  alloc((size_t)(N + 1) * 4);
  int*   bcnt  = (int*)  alloc((size_t)(NB + 1) * 4);
  int*   boff  = (int*)  alloc((size_t)(NB + 1) * 4);
  int*   bfill = (int*)  alloc((size_t)NB * 16 * 4);   // 64B-padded claim counters
  int*   gst   = (int*)  alloc((size_t)(G + 1) * 4);
  int*   ssrc  = (int*)  alloc((size_t)E * 4);
  u16*   wth   = (u16*)  alloc((size_t)4 * 16384 * 2);
  u16*   wtl   = (u16*)  alloc((size_t)4 * 16384 * 2);
  float* pmx   = (float*)alloc((size_t)G * PSPLIT * 128 * 4);
  float* psm   = (float*)alloc((size_t)G * PSPLIT * 128 * 4);
  u16*   hw    = (u16*)  alloc((size_t)N * 128 * 2);   // fp16 message buffer, sliced [8][N][16]
  u32*   h     = (u32*)  alloc((size_t)N * 64 * 4);    // fp16-packed activations, sliced
  unsigned* tmp = (unsigned*)hw;   // alias: tmp (E*4=6.4MB) dead before first gemm writes hw (25.6MB)

  hipMemsetAsync(bcnt, 0, (size_t)(NB + 1) * 4, stream);
  hipMemsetAsync(bfill, 0, (size_t)NB * 16 * 4, stream);

  k_cvtw <<<256, 256, 0, stream>>>(W[0], W[1], W[2], W[3], wth, wtl);
  k_bhist<<<128, 256, NB * 4, stream>>>(ei + E, bcnt, E, NB, batch, gst, N, G);
  k_bscan<<<1, 256, 0, stream>>>(bcnt, boff, NB, E, rp, N);
  k_bscat<<<(E + CHUNK - 1) / CHUNK, 256, 0, stream>>>(ei, boff, bfill, tmp, E, NB);
  k_bfin <<<NB, 256, 0, stream>>>(tmp, boff, ssrc, rp, dinv, N);

  int gemmG = (N + 127) / 128;
  int aggG  = 8 * ((N + 31) / 32);         // 8 slices x node-octs (32 nodes/block), slice = bid & 7
  const float* hin = x;
  for (int l = 0; l < 4; ++l){
    k_gemm<<<gemmG, 256, 0, stream>>>(hin, wth + (l << 14), wtl + (l << 14), dinv, hw, N, l > 0);
    k_agg <<<aggG, 256, 0, stream>>>(hw, rp, ssrc, dinv, B[l], h, N);
    hin = (const float*)h;
  }
  k_pool1<<<G * PSPLIT, 256, 0, stream>>>(h, gst, pmx, psm, N);
  k_head <<<G, 128, 0, stream>>>(pmx, psm, gst, Wl, bl, out);
}

// Round 12
// 633.455 us; speedup vs baseline: 1.6081x; 1.1046x over previous
//
// R21: sliced agg with 32 nodes/wave (2 lanes/node, v4u) + 4-deep batched MLP.
#include <hip/hip_runtime.h>
#include <hip/hip_bf16.h>
#include <math.h>

#define PSPLIT 8
#define BSH 8                  // bucket = dst >> BSH  (256 dsts/bucket)
#define NBMAX 512              // max buckets (N <= 131072, matches 17-bit src pack)
#define CHUNK 8192             // edges per bscat block (32KB LDS staging)
#define AST 40                 // LDS row stride in shorts (80B: 16B-aligned, 2-way banks max)

typedef float v4f __attribute__((ext_vector_type(4)));
typedef float v2f __attribute__((ext_vector_type(2)));
typedef unsigned int v4u __attribute__((ext_vector_type(4)));
typedef unsigned int v2u __attribute__((ext_vector_type(2)));
typedef __attribute__((ext_vector_type(8))) short bf8;
typedef __attribute__((ext_vector_type(4))) float f4;
typedef unsigned short u16;
typedef unsigned int u32;

static inline size_t align_up(size_t x, size_t a){ return (x + a - 1) & ~(a - 1); }

__device__ inline void bf_split(float v, u16& hi, u16& lo){
  __hip_bfloat16 h = __float2bfloat16(v);
  float hf = __bfloat162float(h);
  __hip_bfloat16 l = __float2bfloat16(v - hf);
  hi = *(u16*)&h; lo = *(u16*)&l;
}

// fused fp16->f32 convert + accumulate: a += (float)lo16(p) / hi16(p).
__device__ inline void fmixlo(float& a, u32 p){
  asm("v_fma_mix_f32 %0, %1, 1.0, %0 op_sel:[0,0,0] op_sel_hi:[1,0,0]" : "+v"(a) : "v"(p));
}
__device__ inline void fmixhi(float& a, u32 p){
  asm("v_fma_mix_f32 %0, %1, 1.0, %0 op_sel:[1,0,0] op_sel_hi:[1,0,0]" : "+v"(a) : "v"(p));
}

__device__ inline float f16lo(u32 p){ u16 q = (u16)p; return (float)*(_Float16*)&q; }
__device__ inline float f16hi(u32 p){ u16 q = (u16)(p >> 16); return (float)*(_Float16*)&q; }

// fast tanh: 1 - 2/(exp2(2*log2e*x)+1).  v_exp+v_rcp, ~4e-7 abs err, inf/NaN-safe.
__device__ inline float tanh_fast(float x){
  float u = __builtin_amdgcn_exp2f(x * 2.8853900817779268f);
  float q = __builtin_amdgcn_rcpf(u + 1.0f);
  return fmaf(-2.0f, q, 1.0f);
}

// ---------------- graph prep: bucketed CSR build ----------------

__global__ __launch_bounds__(256) void k_bhist(const int* __restrict__ col, int* __restrict__ bcnt,
                                               int E, int NB,
                                               const int* __restrict__ batch, int* __restrict__ gstart,
                                               int n, int G){
  extern __shared__ int lh[];
  for (int i = threadIdx.x; i < NB; i += 256) lh[i] = 0;
  __syncthreads();
  for (int e = blockIdx.x * 256 + threadIdx.x; e < E; e += gridDim.x * 256)
    atomicAdd(&lh[col[e] >> BSH], 1);
  __syncthreads();
  for (int i = threadIdx.x; i < NB; i += 256){
    int v = lh[i];
    if (v) atomicAdd(&bcnt[i], v);
  }
  // fused gstart
  for (int i = blockIdx.x * 256 + threadIdx.x; i < n; i += gridDim.x * 256){
    int cb = batch[i];
    if (i == 0){ for (int g = 0; g <= cb; ++g) gstart[g] = 0; }
    else { int pb = batch[i - 1]; for (int g = pb + 1; g <= cb; ++g) gstart[g] = i; }
    if (i == n - 1){ for (int g = cb + 1; g <= G; ++g) gstart[g] = n; }
  }
}

__global__ void k_bscan(const int* __restrict__ bcnt, int* __restrict__ boff, int NB, int E,
                        int* __restrict__ rp, int N){
  __shared__ int sd[256];
  int t = threadIdx.x;
  int c[16]; int s = 0;
  const int PT = (NB + 255) / 256;   // <= 2 at BSH=8
  for (int j = 0; j < PT; ++j){ int i = t * PT + j; c[j] = (i < NB) ? bcnt[i] : 0; s += c[j]; }
  sd[t] = s; __syncthreads();
  for (int off = 1; off < 256; off <<= 1){
    int v = sd[t];
    if (t >= off) v += sd[t - off];
    __syncthreads(); sd[t] = v; __syncthreads();
  }
  int run = sd[t] - s;
  for (int j = 0; j < PT; ++j){ int i = t * PT + j; if (i < NB) boff[i] = run; run += c[j]; }
  if (t == 255){ boff[NB] = run; rp[N] = E; }
}

// LDS-staged multisplit scatter (verified R5): coalesced full-line copy-out.
__global__ __launch_bounds__(256) void k_bscat(const int* __restrict__ ei, const int* __restrict__ boff,
                                               int* __restrict__ bfill, unsigned* __restrict__ tmp,
                                               int E, int NB){
  __shared__ int lh[NBMAX], loff[NBMAX], gb[NBMAX], lfil[NBMAX];
  __shared__ int sd[256];
  __shared__ int sumA;
  __shared__ u32 stg[CHUNK];
  int t = threadIdx.x;
  const int* col = ei + E;
  int c0 = blockIdx.x * CHUNK;
  int c1 = c0 + CHUNK; if (c1 > E) c1 = E;

  for (int i = t; i < NBMAX; i += 256){ lh[i] = 0; lfil[i] = 0; }
  __syncthreads();
  // pass 1: local histogram
  for (int e = c0 + t; e < c1; e += 256)
    atomicAdd(&lh[col[e] >> BSH], 1);
  __syncthreads();
  // exclusive scan of lh[0..511] -> loff (two 256-cell tiers)
  sd[t] = lh[t]; __syncthreads();
  for (int off = 1; off < 256; off <<= 1){
    int v = sd[t];
    if (t >= off) v += sd[t - off];
    __syncthreads(); sd[t] = v; __syncthreads();
  }
  loff[t] = sd[t] - lh[t];
  if (t == 255) sumA = sd[255];
  __syncthreads();
  int lb = lh[256 + t];
  sd[t] = lb; __syncthreads();
  for (int off = 1; off < 256; off <<= 1){
    int v = sd[t];
    if (t >= off) v += sd[t - off];
    __syncthreads(); sd[t] = v; __syncthreads();
  }
  loff[256 + t] = sumA + sd[t] - lb;
  // claim global ranges
  for (int i = t; i < NB; i += 256){
    int c = lh[i];
    gb[i] = c ? (boff[i] + atomicAdd(&bfill[i * 16], c)) : 0;
  }
  __syncthreads();
  // pass 2: rank + stage
  for (int e = c0 + t; e < c1; e += 256){
    int d = col[e], s = ei[e];
    int b = d >> BSH;
    int p = atomicAdd(&lfil[b], 1);
    stg[loff[b] + p] = (unsigned)s | ((unsigned)(d & 255) << 17);
  }
  __syncthreads();
  // copy-out: wave w handles buckets w, w+4, ... (coalesced per-bucket runs)
  int wv = t >> 6, lane = t & 63;
  for (int b = wv; b < NB; b += 4){
    int len = lh[b];
    if (!len) continue;
    int base = gb[b], lo = loff[b];
    for (int j = lane; j < len; j += 64) tmp[base + j] = stg[lo + j];
  }
}

// per-bucket 256-bin counting sort (verified R5).
__global__ __launch_bounds__(256) void k_bfin(const unsigned* __restrict__ tmp, const int* __restrict__ boff,
                                              int* __restrict__ ssrc, int* __restrict__ rp,
                                              float* __restrict__ dinv, int N){
  int b = blockIdx.x;
  int d0 = b << BSH;
  int lim = N - d0; if (lim > 256) lim = 256;
  __shared__ int dcnt[256], dexc[256], lfill[256];
  int t = threadIdx.x;
  dcnt[t] = 0; lfill[t] = 0;
  __syncthreads();
  int lo = boff[b], hi = boff[b + 1];
  for (int i = lo + t; i < hi; i += 256) atomicAdd(&dcnt[tmp[i] >> 17], 1);
  __syncthreads();
  int cme = dcnt[t];
  dexc[t] = cme; __syncthreads();
  for (int off = 1; off < 256; off <<= 1){
    int v = dexc[t];
    if (t >= off) v += dexc[t - off];
    __syncthreads(); dexc[t] = v; __syncthreads();
  }
  int excl = dexc[t] - cme;
  __syncthreads();
  dexc[t] = excl;
  if (t < lim){
    int d = d0 + t;
    rp[d] = lo + excl;
    double dd = (double)(cme + 1);               // +1 self-loop
    dinv[d] = (float)(1.0 / sqrt(dd));
  }
  __syncthreads();
  for (int i = lo + t; i < hi; i += 256){
    unsigned r = tmp[i];
    int l = r >> 17;
    int pos = dexc[l] + atomicAdd(&lfill[l], 1);
    ssrc[lo + pos] = (int)(r & 0x1FFFFu);
  }
}

// ---------------- W conversion: f32 [k][n] -> bf16 hi/lo TRANSPOSED [l][n][k] ----------------

__global__ __launch_bounds__(256) void k_cvtw(const float* __restrict__ w0, const float* __restrict__ w1,
                                              const float* __restrict__ w2, const float* __restrict__ w3,
                                              u16* __restrict__ wth, u16* __restrict__ wtl){
  int id = blockIdx.x * 256 + threadIdx.x;
  if (id >= 4 * 16384) return;
  int l = id >> 14, rem = id & 16383, k = rem >> 7, nn = rem & 127;
  const float* Wsrc = (l == 0) ? w0 : (l == 1) ? w1 : (l == 2) ? w2 : w3;
  float v = Wsrc[k * 128 + nn];
  u16 hi, lo; bf_split(v, hi, lo);
  wth[(l << 14) + nn * 128 + k] = hi;
  wtl[(l << 14) + nn * 128 + k] = lo;
}

// ---------------- GEMM (MFMA): C[N,128] = (A[N,128] @ W[128,128]) * dinv[row] ----------------
// Verified structure (R12/R7). Split-bf16 3-term MFMA, single code path.
// packed=0: A f32 row-major. packed=1: A fp16-packed feature-sliced [8][n][16].
// C written feature-sliced [8][n][16] fp16 (verified R8, absmax 7.6e-6).

__global__ __launch_bounds__(256, 4) void k_gemm(const float* __restrict__ A,
                                                 const u16* __restrict__ wth, const u16* __restrict__ wtl,
                                                 const float* __restrict__ dinv,
                                                 u16* __restrict__ C, int n, int packed){
  __shared__ u16 Ah[128 * AST], Al[128 * AST], Wh[128 * AST], Wl[128 * AST];
  int t = threadIdx.x;
  int r0 = blockIdx.x * 128;
  int wv = t >> 6, lane = t & 63;
  int q = lane >> 4, ln = lane & 15;

  int srow = t >> 1;               // 0..127
  int shalf = (t & 1) * 16;        // k-offset within 32-chunk
  int grow = r0 + srow; if (grow > n - 1) grow = n - 1;
  const float* ga = A + (size_t)grow * 128 + shalf;   // f32 path (layer 0)
  const u16* gwh = wth + srow * 128 + shalf;
  const u16* gwl = wtl + srow * 128 + shalf;

  f4 acc[2][8];
  #pragma unroll
  for (int mt = 0; mt < 2; ++mt)
    #pragma unroll
    for (int nt = 0; nt < 8; ++nt) acc[mt][nt] = (f4)(0.f);

  for (int c = 0; c < 4; ++c){
    __syncthreads();
    // stage A chunk: 16 elems per thread -> hi/lo bf16 planes
    {
      u16* ah = &Ah[srow * AST + shalf];
      u16* al = &Al[srow * AST + shalf];
      if (packed){
        // sliced layout: features [32c+shalf, +16) = slice 2c + shalf/16, u32 offset 0..7
        const u32* gp32 = (const u32*)A + ((size_t)(2 * c + (shalf >> 4)) * n + grow) * 8;
        v4u vv0 = *(const v4u*)gp32;
        v4u vv1 = *(const v4u*)(gp32 + 4);
        u32 w_[8] = {vv0.x, vv0.y, vv0.z, vv0.w, vv1.x, vv1.y, vv1.z, vv1.w};
        #pragma unroll
        for (int i = 0; i < 4; ++i){
          u32 wa = w_[i * 2], wb = w_[i * 2 + 1];
          float x0 = f16lo(wa), x1 = f16hi(wa), x2 = f16lo(wb), x3 = f16hi(wb);
          u16 h0,h1,h2,h3,l0,l1,l2,l3;
          bf_split(x0, h0, l0); bf_split(x1, h1, l1);
          bf_split(x2, h2, l2); bf_split(x3, h3, l3);
          ushort4 hv = {h0,h1,h2,h3}, lv = {l0,l1,l2,l3};
          *(ushort4*)&ah[i * 4] = hv;
          *(ushort4*)&al[i * 4] = lv;
        }
      } else {
        const float4* gp = (const float4*)(ga + c * 32);
        #pragma unroll
        for (int i = 0; i < 4; ++i){
          float4 v = gp[i];
          u16 h0,h1,h2,h3,l0,l1,l2,l3;
          bf_split(v.x, h0, l0); bf_split(v.y, h1, l1);
          bf_split(v.z, h2, l2); bf_split(v.w, h3, l3);
          ushort4 hv = {h0,h1,h2,h3}, lv = {l0,l1,l2,l3};
          *(ushort4*)&ah[i * 4] = hv;
          *(ushort4*)&al[i * 4] = lv;
        }
      }
    }
    // stage W^T chunk
    {
      const u16* ph = gwh + c * 32;
      const u16* pl = gwl + c * 32;
      bf8 h0 = *(const bf8*)ph, h1 = *(const bf8*)(ph + 8);
      bf8 l0 = *(const bf8*)pl, l1 = *(const bf8*)(pl + 8);
      *(bf8*)&Wh[srow * AST + shalf] = h0; *(bf8*)&Wh[srow * AST + shalf + 8] = h1;
      *(bf8*)&Wl[srow * AST + shalf] = l0; *(bf8*)&Wl[srow * AST + shalf + 8] = l1;
    }
    __syncthreads();

    bf8 afh[2], afl[2];
    #pragma unroll
    for (int mt = 0; mt < 2; ++mt){
      int row = wv * 32 + mt * 16 + ln;
      afh[mt] = *(const bf8*)&Ah[row * AST + q * 8];
      afl[mt] = *(const bf8*)&Al[row * AST + q * 8];
    }
    #pragma unroll
    for (int nt = 0; nt < 8; ++nt){
      int wn = nt * 16 + ln;
      bf8 wfh = *(const bf8*)&Wh[wn * AST + q * 8];
      bf8 wfl = *(const bf8*)&Wl[wn * AST + q * 8];
      #pragma unroll
      for (int mt = 0; mt < 2; ++mt){
        acc[mt][nt] = __builtin_amdgcn_mfma_f32_16x16x32_bf16(afh[mt], wfh, acc[mt][nt], 0, 0, 0);
        acc[mt][nt] = __builtin_amdgcn_mfma_f32_16x16x32_bf16(afl[mt], wfh, acc[mt][nt], 0, 0, 0);
        acc[mt][nt] = __builtin_amdgcn_mfma_f32_16x16x32_bf16(afh[mt], wfl, acc[mt][nt], 0, 0, 0);
      }
    }
  }

  #pragma unroll
  for (int mt = 0; mt < 2; ++mt){
    int base_m = r0 + wv * 32 + mt * 16 + q * 4;
    float dv[4];
    #pragma unroll
    for (int reg = 0; reg < 4; ++reg){
      int row = base_m + reg;
      dv[reg] = (row < n) ? dinv[row] : 0.f;
    }
    #pragma unroll
    for (int nt = 0; nt < 8; ++nt){
      u16* Cs = C + (size_t)nt * n * 16;       // slice nt
      #pragma unroll
      for (int reg = 0; reg < 4; ++reg){
        int row = base_m + reg;
        if (row < n){
          _Float16 hv = (_Float16)(acc[mt][nt][reg] * dv[reg]);
          Cs[(size_t)row * 16 + ln] = *(u16*)&hv;
        }
      }
    }
  }
}

// ---------------- aggregate: h_out = tanh(dinv[d]*(sum hw'[src] + hw'[d]) + b) ----------------
// R21: feature-sliced (L2-resident, FETCH ~48MB verified R11) with 32 NODES PER WAVE:
// 2 lanes per node, v4u = 16B/lane = half a 32B slice-row. Unroll 4 with batched loads
// (4 ssrc then 4 v4u gathers in flight) -> ~8x fewer latency-exposed iterations than R20
// (which was latency-bound at 108us: VALUBusy 38%, 692 GB/s, 2-deep MLP).

__global__ __launch_bounds__(256) void k_agg(const u16* __restrict__ hwp, const int* __restrict__ rp,
                                             const int* __restrict__ ssrc,
                                             const float* __restrict__ dinv, const float* __restrict__ bias,
                                             u32* __restrict__ hout, int n){
  int slice = blockIdx.x & 7;
  int lane = threadIdx.x & 63;
  int half = lane & 1;                 // which v4u of the 32B slice-row
  int node = (blockIdx.x >> 3) * 128 + (threadIdx.x >> 6) * 32 + (lane >> 1);
  size_t sstr = (size_t)n * 8;         // slice stride in u32
  const v4u* base = (const v4u*)((const u32*)hwp + (size_t)slice * sstr) + half;  // row = 2 v4u

  bool valid = node < n;
  int ee = valid ? rp[node] : 0;
  int e1 = valid ? rp[node + 1] : 0;
  float a0 = 0.f, a1 = 0.f, a2 = 0.f, a3 = 0.f, a4 = 0.f, a5 = 0.f, a6 = 0.f, a7 = 0.f;

  #define FMIX8(P) do{ \
    fmixlo(a0, (P).x); fmixhi(a1, (P).x); fmixlo(a2, (P).y); fmixhi(a3, (P).y); \
    fmixlo(a4, (P).z); fmixhi(a5, (P).z); fmixlo(a6, (P).w); fmixhi(a7, (P).w); }while(0)

  for (; ee + 4 <= e1; ee += 4){
    int s0 = ssrc[ee], s1 = ssrc[ee + 1], s2 = ssrc[ee + 2], s3 = ssrc[ee + 3];
    v4u p0 = base[(size_t)s0 * 2];
    v4u p1 = base[(size_t)s1 * 2];
    v4u p2 = base[(size_t)s2 * 2];
    v4u p3 = base[(size_t)s3 * 2];
    FMIX8(p0); FMIX8(p1); FMIX8(p2); FMIX8(p3);
  }
  for (; ee < e1; ++ee){
    int s0 = ssrc[ee];
    v4u p0 = base[(size_t)s0 * 2];
    FMIX8(p0);
  }
  if (valid){
    v4u p = base[(size_t)node * 2];    // self term (already * dinv[node])
    FMIX8(p);
    float di = dinv[node];
    const float* bp = bias + slice * 16 + half * 8;
    v4f b0 = *(const v4f*)bp;
    v4f b1 = *(const v4f*)(bp + 4);
    float r0 = tanh_fast(fmaf(a0, di, b0.x));
    float r1 = tanh_fast(fmaf(a1, di, b0.y));
    float r2 = tanh_fast(fmaf(a2, di, b0.z));
    float r3 = tanh_fast(fmaf(a3, di, b0.w));
    float r4 = tanh_fast(fmaf(a4, di, b1.x));
    float r5 = tanh_fast(fmaf(a5, di, b1.y));
    float r6 = tanh_fast(fmaf(a6, di, b1.z));
    float r7 = tanh_fast(fmaf(a7, di, b1.w));
    _Float16 f0 = (_Float16)r0, f1 = (_Float16)r1, f2 = (_Float16)r2, f3 = (_Float16)r3;
    _Float16 f4_ = (_Float16)r4, f5 = (_Float16)r5, f6 = (_Float16)r6, f7 = (_Float16)r7;
    v4u pv;
    pv.x = ((u32)(*(u16*)&f1) << 16) | (u32)(*(u16*)&f0);
    pv.y = ((u32)(*(u16*)&f3) << 16) | (u32)(*(u16*)&f2);
    pv.z = ((u32)(*(u16*)&f5) << 16) | (u32)(*(u16*)&f4_);
    pv.w = ((u32)(*(u16*)&f7) << 16) | (u32)(*(u16*)&f6);
    v4u* dst = (v4u*)((u32*)hout + (size_t)slice * sstr) + (size_t)node * 2 + half;
    __builtin_nontemporal_store(pv, dst);
  }
  #undef FMIX8
}

// ---------------- pool: stage 1 partial max/sum over fp16-packed SLICED h ----------------

__global__ __launch_bounds__(256) void k_pool1(const u32* __restrict__ h, const int* __restrict__ gstart,
                                               float* __restrict__ pmx, float* __restrict__ psm, int n){
  int g = blockIdx.x >> 3, s = blockIdx.x & (PSPLIT - 1);
  int t = threadIdx.x;
  int fq = t & 31;             // feature quad (4 features = 2 u32); sliced addr, identity pmx map
  int rw = t >> 5;             // row slot 0..7
  int i0 = gstart[g], i1 = gstart[g + 1];
  int len = i1 - i0;
  int chunk = (len + PSPLIT - 1) / PSPLIT;
  int a = i0 + s * chunk;
  int b = a + chunk; if (b > i1) b = i1;

  const u32* sb = h + (size_t)(fq >> 2) * n * 8 + (fq & 3) * 2;   // slice base + quad offset
  v4f mx = (v4f)(-INFINITY), sm = (v4f)(0.f);
  for (int i = a + rw; i < b; i += 8){
    v2u p = *(const v2u*)(sb + (size_t)i * 8);
    float x0 = f16lo(p.x), x1 = f16hi(p.x), x2 = f16lo(p.y), x3 = f16hi(p.y);
    mx.x = fmaxf(mx.x, x0); mx.y = fmaxf(mx.y, x1);
    mx.z = fmaxf(mx.z, x2); mx.w = fmaxf(mx.w, x3);
    sm.x += x0; sm.y += x1; sm.z += x2; sm.w += x3;
  }
  __shared__ v4f smx[8][32], ssm[8][32];
  smx[rw][fq] = mx; ssm[rw][fq] = sm;
  __syncthreads();
  if (rw == 0){
    #pragma unroll
    for (int r2 = 1; r2 < 8; ++r2){
      v4f m2 = smx[r2][fq], s2 = ssm[r2][fq];
      mx.x = fmaxf(mx.x, m2.x); mx.y = fmaxf(mx.y, m2.y);
      mx.z = fmaxf(mx.z, m2.z); mx.w = fmaxf(mx.w, m2.w);
      sm += s2;
    }
    ((v4f*)pmx)[(size_t)blockIdx.x * 32 + fq] = mx;
    ((v4f*)psm)[(size_t)blockIdx.x * 32 + fq] = sm;
  }
}

__global__ __launch_bounds__(128) void k_head(const float* __restrict__ pmx, const float* __restrict__ psm,
                                              const int* __restrict__ gstart,
                                              const float* __restrict__ Wl, const float* __restrict__ bl,
                                              float* __restrict__ out){
  int g = blockIdx.x, f = threadIdx.x;
  float mx = -INFINITY, sm = 0.f;
  #pragma unroll
  for (int s = 0; s < PSPLIT; ++s){
    mx = fmaxf(mx, pmx[((size_t)g * PSPLIT + s) * 128 + f]);
    sm += psm[((size_t)g * PSPLIT + s) * 128 + f];
  }
  int cnt = gstart[g + 1] - gstart[g];
  if (cnt <= 0) mx = 0.f;
  float mn = sm / (float)(cnt > 0 ? cnt : 1);
  float contrib = mx * Wl[f] + mn * Wl[128 + f];
  for (int o = 32; o > 0; o >>= 1) contrib += __shfl_down(contrib, o);
  __shared__ float sred[2];
  if ((f & 63) == 0) sred[f >> 6] = contrib;
  __syncthreads();
  if (f == 0) out[g] = sred[0] + sred[1] + bl[0];
}

// ---------------- launch ----------------

extern "C" void kernel_launch(void* const* d_in, const int* in_sizes, int n_in,
                              void* d_out, int out_size, void* d_ws, size_t ws_size,
                              hipStream_t stream){
  const float* x     = (const float*)d_in[0];
  const int*   ei    = (const int*)d_in[1];
  const int*   batch = (const int*)d_in[2];
  const float* W[4]  = {(const float*)d_in[3], (const float*)d_in[5], (const float*)d_in[7], (const float*)d_in[9]};
  const float* B[4]  = {(const float*)d_in[4], (const float*)d_in[6], (const float*)d_in[8], (const float*)d_in[10]};
  const float* Wl    = (const float*)d_in[11];
  const float* bl    = (const float*)d_in[12];
  float* out = (float*)d_out;

  int N = in_sizes[0] / 128;
  int E = in_sizes[1] / 2;
  int G = out_size;
  int NB = (N + 255) >> BSH;

  char* ws = (char*)d_ws;
  size_t off = 0;
  auto alloc = [&](size_t bytes) -> void* {
    void* p = ws + off; off = align_up(off + bytes, 256); return p;
  };
  float* dinv  = (float*)alloc((size_t)N * 4);
  int*   rp    = (int*)  alloc((size_t)(N + 1) * 4);
  int*   bcnt  = (int*)  alloc((size_t)(NB + 1) * 4);
  int*   boff  = (int*)  alloc((size_t)(NB + 1) * 4);
  int*   bfill = (int*)  alloc((size_t)NB * 16 * 4);   // 64B-padded claim counters
  int*   gst   = (int*)  alloc((size_t)(G + 1) * 4);
  int*   ssrc  = (int*)  alloc((size_t)E * 4);
  u16*   wth   = (u16*)  alloc((size_t)4 * 16384 * 2);
  u16*   wtl   = (u16*)  alloc((size_t)4 * 16384 * 2);
  float* pmx   = (float*)alloc((size_t)G * PSPLIT * 128 * 4);
  float* psm   = (float*)alloc((size_t)G * PSPLIT * 128 * 4);
  u16*   hw    = (u16*)  alloc((size_t)N * 128 * 2);   // fp16 message buffer, sliced [8][N][16]
  u32*   h     = (u32*)  alloc((size_t)N * 64 * 4);    // fp16-packed activations, sliced
  unsigned* tmp = (unsigned*)hw;   // alias: tmp (E*4=6.4MB) dead before first gemm writes hw (25.6MB)

  hipMemsetAsync(bcnt, 0, (size_t)(NB + 1) * 4, stream);
  hipMemsetAsync(bfill, 0, (size_t)NB * 16 * 4, stream);

  k_cvtw <<<256, 256, 0, stream>>>(W[0], W[1], W[2], W[3], wth, wtl);
  k_bhist<<<128, 256, NB * 4, stream>>>(ei + E, bcnt, E, NB, batch, gst, N, G);
  k_bscan<<<1, 256, 0, stream>>>(bcnt, boff, NB, E, rp, N);
  k_bscat<<<(E + CHUNK - 1) / CHUNK, 256, 0, stream>>>(ei, boff, bfill, tmp, E, NB);
  k_bfin <<<NB, 256, 0, stream>>>(tmp, boff, ssrc, rp, dinv, N);

  int gemmG = (N + 127) / 128;
  int aggG  = 8 * ((N + 127) / 128);       // 8 slices x 128-node blocks (32 nodes/wave), slice = bid & 7
  const float* hin = x;
  for (int l = 0; l < 4; ++l){
    k_gemm<<<gemmG, 256, 0, stream>>>(hin, wth + (l << 14), wtl + (l << 14), dinv, hw, N, l > 0);
    k_agg <<<aggG, 256, 0, stream>>>(hw, rp, ssrc, dinv, B[l], h, N);
    hin = (const float*)h;
  }
  k_pool1<<<G * PSPLIT, 256, 0, stream>>>(h, gst, pmx, psm, N);
  k_head <<<G, 128, 0, stream>>>(pmx, psm, gst, Wl, bl, out);
}

// Round 13
// 528.538 us; speedup vs baseline: 1.9273x; 1.1985x over previous
//
// R22: R7-revert (verified 535us: full-row agg at fill wall, fp16 hw/h) + pipelined
// A-prefetch in gemm (single change vs R7 for attribution).
#include <hip/hip_runtime.h>
#include <hip/hip_bf16.h>
#include <math.h>

#define PSPLIT 8
#define BSH 8                  // bucket = dst >> BSH  (256 dsts/bucket)
#define NBMAX 512              // max buckets (N <= 131072, matches 17-bit src pack)
#define CHUNK 8192             // edges per bscat block (32KB LDS staging)
#define AST 40                 // LDS row stride in shorts (80B: 16B-aligned, 2-way banks max)

typedef float v4f __attribute__((ext_vector_type(4)));
typedef float v2f __attribute__((ext_vector_type(2)));
typedef unsigned int v4u __attribute__((ext_vector_type(4)));
typedef unsigned int v2u __attribute__((ext_vector_type(2)));
typedef __attribute__((ext_vector_type(8))) short bf8;
typedef __attribute__((ext_vector_type(4))) float f4;
typedef unsigned short u16;
typedef unsigned int u32;

static inline size_t align_up(size_t x, size_t a){ return (x + a - 1) & ~(a - 1); }

__device__ inline void bf_split(float v, u16& hi, u16& lo){
  __hip_bfloat16 h = __float2bfloat16(v);
  float hf = __bfloat162float(h);
  __hip_bfloat16 l = __float2bfloat16(v - hf);
  hi = *(u16*)&h; lo = *(u16*)&l;
}

// fused fp16->f32 convert + accumulate: a += (float)lo16(p) / hi16(p).
__device__ inline void fmixlo(float& a, u32 p){
  asm("v_fma_mix_f32 %0, %1, 1.0, %0 op_sel:[0,0,0] op_sel_hi:[1,0,0]" : "+v"(a) : "v"(p));
}
__device__ inline void fmixhi(float& a, u32 p){
  asm("v_fma_mix_f32 %0, %1, 1.0, %0 op_sel:[1,0,0] op_sel_hi:[1,0,0]" : "+v"(a) : "v"(p));
}

__device__ inline float f16lo(u32 p){ u16 q = (u16)p; return (float)*(_Float16*)&q; }
__device__ inline float f16hi(u32 p){ u16 q = (u16)(p >> 16); return (float)*(_Float16*)&q; }

// fast tanh: 1 - 2/(exp2(2*log2e*x)+1).  v_exp+v_rcp, ~4e-7 abs err, inf/NaN-safe.
__device__ inline float tanh_fast(float x){
  float u = __builtin_amdgcn_exp2f(x * 2.8853900817779268f);
  float q = __builtin_amdgcn_rcpf(u + 1.0f);
  return fmaf(-2.0f, q, 1.0f);
}

// ---------------- graph prep: bucketed CSR build ----------------
// R17 multisplit (verified R5): LDS-staged, coalesced full-line copy-out.

__global__ __launch_bounds__(256) void k_bhist(const int* __restrict__ col, int* __restrict__ bcnt,
                                               int E, int NB,
                                               const int* __restrict__ batch, int* __restrict__ gstart,
                                               int n, int G){
  extern __shared__ int lh[];
  for (int i = threadIdx.x; i < NB; i += 256) lh[i] = 0;
  __syncthreads();
  for (int e = blockIdx.x * 256 + threadIdx.x; e < E; e += gridDim.x * 256)
    atomicAdd(&lh[col[e] >> BSH], 1);
  __syncthreads();
  for (int i = threadIdx.x; i < NB; i += 256){
    int v = lh[i];
    if (v) atomicAdd(&bcnt[i], v);
  }
  // fused gstart
  for (int i = blockIdx.x * 256 + threadIdx.x; i < n; i += gridDim.x * 256){
    int cb = batch[i];
    if (i == 0){ for (int g = 0; g <= cb; ++g) gstart[g] = 0; }
    else { int pb = batch[i - 1]; for (int g = pb + 1; g <= cb; ++g) gstart[g] = i; }
    if (i == n - 1){ for (int g = cb + 1; g <= G; ++g) gstart[g] = n; }
  }
}

__global__ void k_bscan(const int* __restrict__ bcnt, int* __restrict__ boff, int NB, int E,
                        int* __restrict__ rp, int N){
  __shared__ int sd[256];
  int t = threadIdx.x;
  int c[16]; int s = 0;
  const int PT = (NB + 255) / 256;   // <= 2 at BSH=8
  for (int j = 0; j < PT; ++j){ int i = t * PT + j; c[j] = (i < NB) ? bcnt[i] : 0; s += c[j]; }
  sd[t] = s; __syncthreads();
  for (int off = 1; off < 256; off <<= 1){
    int v = sd[t];
    if (t >= off) v += sd[t - off];
    __syncthreads(); sd[t] = v; __syncthreads();
  }
  int run = sd[t] - s;
  for (int j = 0; j < PT; ++j){ int i = t * PT + j; if (i < NB) boff[i] = run; run += c[j]; }
  if (t == 255){ boff[NB] = run; rp[N] = E; }
}

// LDS-staged multisplit scatter (verified R5): coalesced full-line copy-out.
__global__ __launch_bounds__(256) void k_bscat(const int* __restrict__ ei, const int* __restrict__ boff,
                                               int* __restrict__ bfill, unsigned* __restrict__ tmp,
                                               int E, int NB){
  __shared__ int lh[NBMAX], loff[NBMAX], gb[NBMAX], lfil[NBMAX];
  __shared__ int sd[256];
  __shared__ int sumA;
  __shared__ u32 stg[CHUNK];
  int t = threadIdx.x;
  const int* col = ei + E;
  int c0 = blockIdx.x * CHUNK;
  int c1 = c0 + CHUNK; if (c1 > E) c1 = E;

  for (int i = t; i < NBMAX; i += 256){ lh[i] = 0; lfil[i] = 0; }
  __syncthreads();
  // pass 1: local histogram
  for (int e = c0 + t; e < c1; e += 256)
    atomicAdd(&lh[col[e] >> BSH], 1);
  __syncthreads();
  // exclusive scan of lh[0..511] -> loff (two 256-cell tiers)
  sd[t] = lh[t]; __syncthreads();
  for (int off = 1; off < 256; off <<= 1){
    int v = sd[t];
    if (t >= off) v += sd[t - off];
    __syncthreads(); sd[t] = v; __syncthreads();
  }
  loff[t] = sd[t] - lh[t];
  if (t == 255) sumA = sd[255];
  __syncthreads();
  int lb = lh[256 + t];
  sd[t] = lb; __syncthreads();
  for (int off = 1; off < 256; off <<= 1){
    int v = sd[t];
    if (t >= off) v += sd[t - off];
    __syncthreads(); sd[t] = v; __syncthreads();
  }
  loff[256 + t] = sumA + sd[t] - lb;
  // claim global ranges
  for (int i = t; i < NB; i += 256){
    int c = lh[i];
    gb[i] = c ? (boff[i] + atomicAdd(&bfill[i * 16], c)) : 0;
  }
  __syncthreads();
  // pass 2: rank + stage
  for (int e = c0 + t; e < c1; e += 256){
    int d = col[e], s = ei[e];
    int b = d >> BSH;
    int p = atomicAdd(&lfil[b], 1);
    stg[loff[b] + p] = (unsigned)s | ((unsigned)(d & 255) << 17);
  }
  __syncthreads();
  // copy-out: wave w handles buckets w, w+4, ... (coalesced per-bucket runs)
  int wv = t >> 6, lane = t & 63;
  for (int b = wv; b < NB; b += 4){
    int len = lh[b];
    if (!len) continue;
    int base = gb[b], lo = loff[b];
    for (int j = lane; j < len; j += 64) tmp[base + j] = stg[lo + j];
  }
}

// per-bucket 256-bin counting sort (verified R5).
__global__ __launch_bounds__(256) void k_bfin(const unsigned* __restrict__ tmp, const int* __restrict__ boff,
                                              int* __restrict__ ssrc, int* __restrict__ rp,
                                              float* __restrict__ dinv, int N){
  int b = blockIdx.x;
  int d0 = b << BSH;
  int lim = N - d0; if (lim > 256) lim = 256;
  __shared__ int dcnt[256], dexc[256], lfill[256];
  int t = threadIdx.x;
  dcnt[t] = 0; lfill[t] = 0;
  __syncthreads();
  int lo = boff[b], hi = boff[b + 1];
  for (int i = lo + t; i < hi; i += 256) atomicAdd(&dcnt[tmp[i] >> 17], 1);
  __syncthreads();
  int cme = dcnt[t];
  dexc[t] = cme; __syncthreads();
  for (int off = 1; off < 256; off <<= 1){
    int v = dexc[t];
    if (t >= off) v += dexc[t - off];
    __syncthreads(); dexc[t] = v; __syncthreads();
  }
  int excl = dexc[t] - cme;
  __syncthreads();
  dexc[t] = excl;
  if (t < lim){
    int d = d0 + t;
    rp[d] = lo + excl;
    double dd = (double)(cme + 1);               // +1 self-loop
    dinv[d] = (float)(1.0 / sqrt(dd));
  }
  __syncthreads();
  for (int i = lo + t; i < hi; i += 256){
    unsigned r = tmp[i];
    int l = r >> 17;
    int pos = dexc[l] + atomicAdd(&lfill[l], 1);
    ssrc[lo + pos] = (int)(r & 0x1FFFFu);
  }
}

// ---------------- W conversion: f32 [k][n] -> bf16 hi/lo TRANSPOSED [l][n][k] ----------------

__global__ __launch_bounds__(256) void k_cvtw(const float* __restrict__ w0, const float* __restrict__ w1,
                                              const float* __restrict__ w2, const float* __restrict__ w3,
                                              u16* __restrict__ wth, u16* __restrict__ wtl){
  int id = blockIdx.x * 256 + threadIdx.x;
  if (id >= 4 * 16384) return;
  int l = id >> 14, rem = id & 16383, k = rem >> 7, nn = rem & 127;
  const float* Wsrc = (l == 0) ? w0 : (l == 1) ? w1 : (l == 2) ? w2 : w3;
  float v = Wsrc[k * 128 + nn];
  u16 hi, lo; bf_split(v, hi, lo);
  wth[(l << 14) + nn * 128 + k] = hi;
  wtl[(l << 14) + nn * 128 + k] = lo;
}

// ---------------- GEMM (MFMA): C[N,128] = (A[N,128] @ W[128,128]) * dinv[row] ----------------
// R7-verified structure (split-bf16 3-term MFMA, single path) + R22 change: A-loads for
// chunk c+1 are issued into registers BEFORE chunk c's MFMA (rotate prefetch), hiding the
// per-chunk HBM/L2 latency that the old {barrier, load, stage, barrier, MFMA} loop exposed
// 4x per block. W loads stay in-loop (64KB table, L2-resident after first block).
// packed=0: A f32 row-major (layer 0). packed=1: A fp16-packed u32 row-major.
// C (=hw) row-major [n][128] fp16.

__global__ __launch_bounds__(256, 4) void k_gemm(const float* __restrict__ A,
                                                 const u16* __restrict__ wth, const u16* __restrict__ wtl,
                                                 const float* __restrict__ dinv,
                                                 u16* __restrict__ C, int n, int packed){
  __shared__ u16 Ah[128 * AST], Al[128 * AST], Wh[128 * AST], Wl[128 * AST];
  int t = threadIdx.x;
  int r0 = blockIdx.x * 128;
  int wv = t >> 6, lane = t & 63;
  int q = lane >> 4, ln = lane & 15;

  int srow = t >> 1;               // 0..127
  int shalf = (t & 1) * 16;        // k-offset within 32-chunk
  int grow = r0 + srow; if (grow > n - 1) grow = n - 1;
  const float* ga = A + (size_t)grow * 128 + shalf;                   // f32 path
  const u32* gap = (const u32*)A + (size_t)grow * 64 + (shalf >> 1);  // packed fp16 path
  const u16* gwh = wth + srow * 128 + shalf;
  const u16* gwl = wtl + srow * 128 + shalf;

  f4 acc[2][8];
  #pragma unroll
  for (int mt = 0; mt < 2; ++mt)
    #pragma unroll
    for (int nt = 0; nt < 8; ++nt) acc[mt][nt] = (f4)(0.f);

  // A-prefetch registers (R22)
  float4 fA0, fA1, fA2, fA3;
  v4u qA0, qA1;
  auto LDA = [&](int c){
    if (packed){
      const v4u* gp = (const v4u*)(gap + c * 16);
      qA0 = gp[0]; qA1 = gp[1];
    } else {
      const float4* gp = (const float4*)(ga + c * 32);
      fA0 = gp[0]; fA1 = gp[1]; fA2 = gp[2]; fA3 = gp[3];
    }
  };
  LDA(0);

  for (int c = 0; c < 4; ++c){
    __syncthreads();
    // stage A chunk from prefetch regs -> hi/lo bf16 planes
    {
      u16* ah = &Ah[srow * AST + shalf];
      u16* al = &Al[srow * AST + shalf];
      if (packed){
        u32 w_[8] = {qA0.x, qA0.y, qA0.z, qA0.w, qA1.x, qA1.y, qA1.z, qA1.w};
        #pragma unroll
        for (int i = 0; i < 4; ++i){
          u32 wa = w_[i * 2], wb = w_[i * 2 + 1];
          float x0 = f16lo(wa), x1 = f16hi(wa), x2 = f16lo(wb), x3 = f16hi(wb);
          u16 h0,h1,h2,h3,l0,l1,l2,l3;
          bf_split(x0, h0, l0); bf_split(x1, h1, l1);
          bf_split(x2, h2, l2); bf_split(x3, h3, l3);
          ushort4 hv = {h0,h1,h2,h3}, lv = {l0,l1,l2,l3};
          *(ushort4*)&ah[i * 4] = hv;
          *(ushort4*)&al[i * 4] = lv;
        }
      } else {
        float4 v_[4] = {fA0, fA1, fA2, fA3};
        #pragma unroll
        for (int i = 0; i < 4; ++i){
          float4 v = v_[i];
          u16 h0,h1,h2,h3,l0,l1,l2,l3;
          bf_split(v.x, h0, l0); bf_split(v.y, h1, l1);
          bf_split(v.z, h2, l2); bf_split(v.w, h3, l3);
          ushort4 hv = {h0,h1,h2,h3}, lv = {l0,l1,l2,l3};
          *(ushort4*)&ah[i * 4] = hv;
          *(ushort4*)&al[i * 4] = lv;
        }
      }
      // stage W^T chunk (in-loop: L2-resident)
      const u16* ph = gwh + c * 32;
      const u16* pl = gwl + c * 32;
      bf8 h0 = *(const bf8*)ph, h1 = *(const bf8*)(ph + 8);
      bf8 l0 = *(const bf8*)pl, l1 = *(const bf8*)(pl + 8);
      *(bf8*)&Wh[srow * AST + shalf] = h0; *(bf8*)&Wh[srow * AST + shalf + 8] = h1;
      *(bf8*)&Wl[srow * AST + shalf] = l0; *(bf8*)&Wl[srow * AST + shalf + 8] = l1;
    }
    if (c < 3) LDA(c + 1);          // issue next-chunk A loads; land during MFMA below
    __syncthreads();

    bf8 afh[2], afl[2];
    #pragma unroll
    for (int mt = 0; mt < 2; ++mt){
      int row = wv * 32 + mt * 16 + ln;
      afh[mt] = *(const bf8*)&Ah[row * AST + q * 8];
      afl[mt] = *(const bf8*)&Al[row * AST + q * 8];
    }
    #pragma unroll
    for (int nt = 0; nt < 8; ++nt){
      int wn = nt * 16 + ln;
      bf8 wfh = *(const bf8*)&Wh[wn * AST + q * 8];
      bf8 wfl = *(const bf8*)&Wl[wn * AST + q * 8];
      #pragma unroll
      for (int mt = 0; mt < 2; ++mt){
        acc[mt][nt] = __builtin_amdgcn_mfma_f32_16x16x32_bf16(afh[mt], wfh, acc[mt][nt], 0, 0, 0);
        acc[mt][nt] = __builtin_amdgcn_mfma_f32_16x16x32_bf16(afl[mt], wfh, acc[mt][nt], 0, 0, 0);
        acc[mt][nt] = __builtin_amdgcn_mfma_f32_16x16x32_bf16(afh[mt], wfl, acc[mt][nt], 0, 0, 0);
      }
    }
  }

  #pragma unroll
  for (int mt = 0; mt < 2; ++mt){
    int base_m = r0 + wv * 32 + mt * 16 + q * 4;
    float dv[4];
    #pragma unroll
    for (int reg = 0; reg < 4; ++reg){
      int row = base_m + reg;
      dv[reg] = (row < n) ? dinv[row] : 0.f;
    }
    #pragma unroll
    for (int nt = 0; nt < 8; ++nt){
      #pragma unroll
      for (int reg = 0; reg < 4; ++reg){
        int row = base_m + reg;
        if (row < n){
          _Float16 hv = (_Float16)(acc[mt][nt][reg] * dv[reg]);
          C[(size_t)row * 128 + nt * 16 + ln] = *(u16*)&hv;
        }
      }
    }
  }
}

// ---------------- aggregate: h_out = tanh(dinv[d]*(sum hw'[src] + hw'[d]) + b) ----------------
// R14 structure (verified best, 59us at the ~3.9 TB/s L2-fill wall, FETCH 192MB ~ 8% over
// the 177MB 8-XCD analytic floor): ONE WAVE PER NODE, 256B fp16 row gather, lane = u32 =
// 2 features. node wave-uniform (readfirstlane) -> scalar rp/ssrc; 16 gathers in flight.
// Output h fp16-packed (verified R6/R7).

__global__ __launch_bounds__(256) void k_agg(const u16* __restrict__ hwp, const int* __restrict__ rp,
                                             const int* __restrict__ ssrc,
                                             const float* __restrict__ dinv, const float* __restrict__ bias,
                                             u32* __restrict__ hout, int n){
  int node = blockIdx.x * 4 + (threadIdx.x >> 6);
  node = __builtin_amdgcn_readfirstlane(node);
  if (node >= n) return;
  int lane = threadIdx.x & 63;
  const u32* hw32 = (const u32*)hwp;          // row = 64 u32 = 256B

  int e0 = rp[node], e1 = rp[node + 1];
  float a0 = 0.f, a1 = 0.f;
  int e = e0;
  while (e + 16 <= e1){
    u32 p[16];
    #pragma unroll
    for (int i = 0; i < 16; ++i){
      int s = ssrc[e + i];
      p[i] = hw32[(size_t)s * 64 + lane];
    }
    #pragma unroll
    for (int i = 0; i < 16; ++i){ fmixlo(a0, p[i]); fmixhi(a1, p[i]); }
    e += 16;
  }
  while (e + 4 <= e1){
    u32 p[4];
    #pragma unroll
    for (int i = 0; i < 4; ++i){
      int s = ssrc[e + i];
      p[i] = hw32[(size_t)s * 64 + lane];
    }
    #pragma unroll
    for (int i = 0; i < 4; ++i){ fmixlo(a0, p[i]); fmixhi(a1, p[i]); }
    e += 4;
  }
  while (e < e1){
    int s = ssrc[e];
    u32 p = hw32[(size_t)s * 64 + lane];
    fmixlo(a0, p); fmixhi(a1, p);
    ++e;
  }
  // self term (already * dinv[node])
  {
    u32 p = hw32[(size_t)node * 64 + lane];
    fmixlo(a0, p); fmixhi(a1, p);
  }
  float di = dinv[node];
  v2f bv = *(const v2f*)(bias + lane * 2);
  float r0 = tanh_fast(fmaf(a0, di, bv.x));
  float r1 = tanh_fast(fmaf(a1, di, bv.y));
  _Float16 f0 = (_Float16)r0, f1 = (_Float16)r1;
  u32 pv = ((u32)(*(u16*)&f1) << 16) | (u32)(*(u16*)&f0);
  __builtin_nontemporal_store(pv, hout + (size_t)node * 64 + lane);
}

// ---------------- pool: stage 1 partial max/sum over fp16-packed h ----------------

__global__ __launch_bounds__(256) void k_pool1(const u32* __restrict__ h, const int* __restrict__ gstart,
                                               float* __restrict__ pmx, float* __restrict__ psm){
  int g = blockIdx.x >> 3, s = blockIdx.x & (PSPLIT - 1);
  int t = threadIdx.x;
  int fq = t & 31;             // feature quad (4 features = 2 u32)
  int rw = t >> 5;             // row slot 0..7
  int i0 = gstart[g], i1 = gstart[g + 1];
  int len = i1 - i0;
  int chunk = (len + PSPLIT - 1) / PSPLIT;
  int a = i0 + s * chunk;
  int b = a + chunk; if (b > i1) b = i1;

  const v2u* hv = (const v2u*)h;   // 32 v2u per row
  v4f mx = (v4f)(-INFINITY), sm = (v4f)(0.f);
  for (int i = a + rw; i < b; i += 8){
    v2u p = hv[(size_t)i * 32 + fq];
    float x0 = f16lo(p.x), x1 = f16hi(p.x), x2 = f16lo(p.y), x3 = f16hi(p.y);
    mx.x = fmaxf(mx.x, x0); mx.y = fmaxf(mx.y, x1);
    mx.z = fmaxf(mx.z, x2); mx.w = fmaxf(mx.w, x3);
    sm.x += x0; sm.y += x1; sm.z += x2; sm.w += x3;
  }
  __shared__ v4f smx[8][32], ssm[8][32];
  smx[rw][fq] = mx; ssm[rw][fq] = sm;
  __syncthreads();
  if (rw == 0){
    #pragma unroll
    for (int r2 = 1; r2 < 8; ++r2){
      v4f m2 = smx[r2][fq], s2 = ssm[r2][fq];
      mx.x = fmaxf(mx.x, m2.x); mx.y = fmaxf(mx.y, m2.y);
      mx.z = fmaxf(mx.z, m2.z); mx.w = fmaxf(mx.w, m2.w);
      sm += s2;
    }
    ((v4f*)pmx)[(size_t)blockIdx.x * 32 + fq] = mx;
    ((v4f*)psm)[(size_t)blockIdx.x * 32 + fq] = sm;
  }
}

__global__ __launch_bounds__(128) void k_head(const float* __restrict__ pmx, const float* __restrict__ psm,
                                              const int* __restrict__ gstart,
                                              const float* __restrict__ Wl, const float* __restrict__ bl,
                                              float* __restrict__ out){
  int g = blockIdx.x, f = threadIdx.x;
  float mx = -INFINITY, sm = 0.f;
  #pragma unroll
  for (int s = 0; s < PSPLIT; ++s){
    mx = fmaxf(mx, pmx[((size_t)g * PSPLIT + s) * 128 + f]);
    sm += psm[((size_t)g * PSPLIT + s) * 128 + f];
  }
  int cnt = gstart[g + 1] - gstart[g];
  if (cnt <= 0) mx = 0.f;
  float mn = sm / (float)(cnt > 0 ? cnt : 1);
  float contrib = mx * Wl[f] + mn * Wl[128 + f];
  for (int o = 32; o > 0; o >>= 1) contrib += __shfl_down(contrib, o);
  __shared__ float sred[2];
  if ((f & 63) == 0) sred[f >> 6] = contrib;
  __syncthreads();
  if (f == 0) out[g] = sred[0] + sred[1] + bl[0];
}

// ---------------- launch ----------------

extern "C" void kernel_launch(void* const* d_in, const int* in_sizes, int n_in,
                              void* d_out, int out_size, void* d_ws, size_t ws_size,
                              hipStream_t stream){
  const float* x     = (const float*)d_in[0];
  const int*   ei    = (const int*)d_in[1];
  const int*   batch = (const int*)d_in[2];
  const float* W[4]  = {(const float*)d_in[3], (const float*)d_in[5], (const float*)d_in[7], (const float*)d_in[9]};
  const float* B[4]  = {(const float*)d_in[4], (const float*)d_in[6], (const float*)d_in[8], (const float*)d_in[10]};
  const float* Wl    = (const float*)d_in[11];
  const float* bl    = (const float*)d_in[12];
  float* out = (float*)d_out;

  int N = in_sizes[0] / 128;
  int E = in_sizes[1] / 2;
  int G = out_size;
  int NB = (N + 255) >> BSH;

  char* ws = (char*)d_ws;
  size_t off = 0;
  auto alloc = [&](size_t bytes) -> void* {
    void* p = ws + off; off = align_up(off + bytes, 256); return p;
  };
  float* dinv  = (float*)alloc((size_t)N * 4);
  int*   rp    = (int*)  alloc((size_t)(N + 1) * 4);
  int*   bcnt  = (int*)  alloc((size_t)(NB + 1) * 4);
  int*   boff  = (int*)  alloc((size_t)(NB + 1) * 4);
  int*   bfill = (int*)  alloc((size_t)NB * 16 * 4);   // 64B-padded claim counters
  int*   gst   = (int*)  alloc((size_t)(G + 1) * 4);
  int*   ssrc  = (int*)  alloc((size_t)E * 4);
  u16*   wth   = (u16*)  alloc((size_t)4 * 16384 * 2);
  u16*   wtl   = (u16*)  alloc((size_t)4 * 16384 * 2);
  float* pmx   = (float*)alloc((size_t)G * PSPLIT * 128 * 4);
  float* psm   = (float*)alloc((size_t)G * PSPLIT * 128 * 4);
  u16*   hw    = (u16*)  alloc((size_t)N * 128 * 2);   // fp16 message buffer, row-major [N][128]
  u32*   h     = (u32*)  alloc((size_t)N * 64 * 4);    // fp16-packed activations, row-major
  unsigned* tmp = (unsigned*)hw;   // alias: tmp (E*4=6.4MB) dead before first gemm writes hw (25.6MB)

  hipMemsetAsync(bcnt, 0, (size_t)(NB + 1) * 4, stream);
  hipMemsetAsync(bfill, 0, (size_t)NB * 16 * 4, stream);

  k_cvtw <<<256, 256, 0, stream>>>(W[0], W[1], W[2], W[3], wth, wtl);
  k_bhist<<<128, 256, NB * 4, stream>>>(ei + E, bcnt, E, NB, batch, gst, N, G);
  k_bscan<<<1, 256, 0, stream>>>(bcnt, boff, NB, E, rp, N);
  k_bscat<<<(E + CHUNK - 1) / CHUNK, 256, 0, stream>>>(ei, boff, bfill, tmp, E, NB);
  k_bfin <<<NB, 256, 0, stream>>>(tmp, boff, ssrc, rp, dinv, N);

  int gemmG = (N + 127) / 128;
  int aggG  = (N + 3) / 4;                 // one wave per node, 4 waves/block
  const float* hin = x;
  for (int l = 0; l < 4; ++l){
    k_gemm<<<gemmG, 256, 0, stream>>>(hin, wth + (l << 14), wtl + (l << 14), dinv, hw, N, l > 0);
    k_agg <<<aggG, 256, 0, stream>>>(hw, rp, ssrc, dinv, B[l], h, N);
    hin = (const float*)h;
  }
  k_pool1<<<G * PSPLIT, 256, 0, stream>>>(h, gst, pmx, psm);
  k_head <<<G, 128, 0, stream>>>(pmx, psm, gst, Wl, bl, out);
}